// Round 2
// baseline (1906.471 us; speedup 1.0000x reference)
//
#include <hip/hip_runtime.h>
#include <hip/hip_bf16.h>
#include <math.h>

#define Bb 2
#define Ss 4096
#define Dd 512
#define Hh 8
#define DHh 64
#define Ff 2048
#define Mm 8192   // Bb*Ss

// ---------------------------------------------------------------------------
// Generic fp32 GEMM: C[M,N] = A[M,K] @ W[K,N] + bias[N], optional ReLU.
// 128x128 block tile, BK=16, 256 threads, 8x8 per thread (split 4+4 rows/cols).
// ---------------------------------------------------------------------------
template<bool RELU>
__global__ __launch_bounds__(256) void gemm_bias(const float* __restrict__ A,
                                                 const float* __restrict__ W,
                                                 const float* __restrict__ bias,
                                                 float* __restrict__ C,
                                                 int M, int N, int K) {
  __shared__ __align__(16) float As[16][128];
  __shared__ __align__(16) float Ws[16][128];
  const int tid = threadIdx.x;
  const int bm = blockIdx.y * 128, bn = blockIdx.x * 128;
  const int tx = tid & 15, ty = tid >> 4;
  const int ar = tid >> 2, ac = (tid & 3) << 2;   // A tile: rows 0..63(+64), 4 cols
  const int wr = tid >> 5, wc = (tid & 31) << 2;  // W tile: rows 0..7(+8), 4 cols
  float acc[8][8] = {};
  const float* Ap0 = A + (size_t)(bm + ar) * K + ac;
  const float* Ap1 = Ap0 + (size_t)64 * K;
  const float* Wp0 = W + (size_t)wr * N + bn + wc;
  const float* Wp1 = Wp0 + (size_t)8 * N;

  for (int k0 = 0; k0 < K; k0 += 16) {
    float4 a0 = *(const float4*)(Ap0 + k0);
    float4 a1 = *(const float4*)(Ap1 + k0);
    float4 w0 = *(const float4*)(Wp0 + (size_t)k0 * N);
    float4 w1 = *(const float4*)(Wp1 + (size_t)k0 * N);
    __syncthreads();  // previous iteration's compute done before overwrite
    As[ac + 0][ar] = a0.x; As[ac + 1][ar] = a0.y;
    As[ac + 2][ar] = a0.z; As[ac + 3][ar] = a0.w;
    As[ac + 0][64 + ar] = a1.x; As[ac + 1][64 + ar] = a1.y;
    As[ac + 2][64 + ar] = a1.z; As[ac + 3][64 + ar] = a1.w;
    *(float4*)&Ws[wr][wc] = w0;
    *(float4*)&Ws[wr + 8][wc] = w1;
    __syncthreads();
#pragma unroll
    for (int kk = 0; kk < 16; ++kk) {
      float av[8], bv[8];
      *(float4*)&av[0] = *(const float4*)&As[kk][ty * 4];
      *(float4*)&av[4] = *(const float4*)&As[kk][64 + ty * 4];
      *(float4*)&bv[0] = *(const float4*)&Ws[kk][tx * 4];
      *(float4*)&bv[4] = *(const float4*)&Ws[kk][64 + tx * 4];
#pragma unroll
      for (int i = 0; i < 8; ++i)
#pragma unroll
        for (int j = 0; j < 8; ++j)
          acc[i][j] = fmaf(av[i], bv[j], acc[i][j]);
    }
  }

  const float4 bia0 = *(const float4*)&bias[bn + tx * 4];
  const float4 bia1 = *(const float4*)&bias[bn + 64 + tx * 4];
  const float bl[8] = {bia0.x, bia0.y, bia0.z, bia0.w, bia1.x, bia1.y, bia1.z, bia1.w};
#pragma unroll
  for (int i = 0; i < 8; ++i) {
    const int row = bm + ((i < 4) ? (ty * 4 + i) : (64 + ty * 4 + i - 4));
    float o[8];
#pragma unroll
    for (int j = 0; j < 8; ++j) {
      o[j] = acc[i][j] + bl[j];
      if (RELU) o[j] = fmaxf(o[j], 0.f);
    }
    *(float4*)&C[(size_t)row * N + bn + tx * 4]      = make_float4(o[0], o[1], o[2], o[3]);
    *(float4*)&C[(size_t)row * N + bn + 64 + tx * 4] = make_float4(o[4], o[5], o[6], o[7]);
  }
}

// ---------------------------------------------------------------------------
// Causal flash attention, fp32. One block per (q-tile of 64 rows, b*h).
// q/k/v/ctx layout: [B,S,D] with head offset h*64. Online softmax.
// ---------------------------------------------------------------------------
__global__ __launch_bounds__(256) void flash_attn(const float* __restrict__ q,
                                                  const float* __restrict__ k,
                                                  const float* __restrict__ v,
                                                  float* __restrict__ ctx) {
  __shared__ __align__(16) float Qt[64][68];  // [d][row]   (transposed)
  __shared__ __align__(16) float Kt[64][68];  // [d][col]   (transposed)
  __shared__ __align__(16) float Vs[64][68];  // [col][d]
  __shared__ __align__(16) float Ps[64][68];  // [row][col]
  const int tid = threadIdx.x;
  const int qt = blockIdx.x, bh = blockIdx.y;
  const int bb = bh >> 3, hh = bh & 7;
  const int q0 = qt * 64;
  const size_t base = (size_t)bb * Ss * Dd + hh * 64;
  const int tx = tid & 15, ty = tid >> 4;
  const int lr = tid >> 2, ld0 = (tid & 3) * 16;  // loader: row 0..63, 16 dims

  {  // load Q tile transposed (once)
    const float* src = q + base + (size_t)(q0 + lr) * Dd + ld0;
#pragma unroll
    for (int i = 0; i < 16; i += 4) {
      float4 t4 = *(const float4*)(src + i);
      Qt[ld0 + i + 0][lr] = t4.x; Qt[ld0 + i + 1][lr] = t4.y;
      Qt[ld0 + i + 2][lr] = t4.z; Qt[ld0 + i + 3][lr] = t4.w;
    }
  }

  float m_run[4], l_run[4], acc[4][4] = {};
#pragma unroll
  for (int i = 0; i < 4; ++i) { m_run[i] = -INFINITY; l_run[i] = 0.f; }

  for (int kt = 0; kt <= qt; ++kt) {
    const int j0 = kt * 64;
    {  // stage K (transposed) and V (natural)
      const float* ksrc = k + base + (size_t)(j0 + lr) * Dd + ld0;
      const float* vsrc = v + base + (size_t)(j0 + lr) * Dd + ld0;
      float4 kreg[4], vreg[4];
#pragma unroll
      for (int i = 0; i < 4; ++i) {
        kreg[i] = *(const float4*)(ksrc + i * 4);
        vreg[i] = *(const float4*)(vsrc + i * 4);
      }
      __syncthreads();  // everyone done with previous tile's LDS
#pragma unroll
      for (int i = 0; i < 4; ++i) {
        Kt[ld0 + i * 4 + 0][lr] = kreg[i].x; Kt[ld0 + i * 4 + 1][lr] = kreg[i].y;
        Kt[ld0 + i * 4 + 2][lr] = kreg[i].z; Kt[ld0 + i * 4 + 3][lr] = kreg[i].w;
        *(float4*)&Vs[lr][ld0 + i * 4] = vreg[i];
      }
      __syncthreads();
    }

    // S = Q K^T (raw dot, scaled after)
    float s[4][4] = {};
#pragma unroll 8
    for (int d = 0; d < 64; ++d) {
      float a0 = Qt[d][ty * 4 + 0], a1 = Qt[d][ty * 4 + 1];
      float a2 = Qt[d][ty * 4 + 2], a3 = Qt[d][ty * 4 + 3];
      float b0 = Kt[d][tx * 4 + 0], b1 = Kt[d][tx * 4 + 1];
      float b2 = Kt[d][tx * 4 + 2], b3 = Kt[d][tx * 4 + 3];
      s[0][0] = fmaf(a0, b0, s[0][0]); s[0][1] = fmaf(a0, b1, s[0][1]);
      s[0][2] = fmaf(a0, b2, s[0][2]); s[0][3] = fmaf(a0, b3, s[0][3]);
      s[1][0] = fmaf(a1, b0, s[1][0]); s[1][1] = fmaf(a1, b1, s[1][1]);
      s[1][2] = fmaf(a1, b2, s[1][2]); s[1][3] = fmaf(a1, b3, s[1][3]);
      s[2][0] = fmaf(a2, b0, s[2][0]); s[2][1] = fmaf(a2, b1, s[2][1]);
      s[2][2] = fmaf(a2, b2, s[2][2]); s[2][3] = fmaf(a2, b3, s[2][3]);
      s[3][0] = fmaf(a3, b0, s[3][0]); s[3][1] = fmaf(a3, b1, s[3][1]);
      s[3][2] = fmaf(a3, b2, s[3][2]); s[3][3] = fmaf(a3, b3, s[3][3]);
    }

    // scale + causal mask (diagonal tile only; -1e9 matches reference exactly
    // after exp underflow)
    const float scale = 0.125f;
#pragma unroll
    for (int i = 0; i < 4; ++i)
#pragma unroll
      for (int j = 0; j < 4; ++j) {
        float sv = s[i][j] * scale;
        if (kt == qt && (tx * 4 + j) > (ty * 4 + i)) sv -= 1e9f;
        s[i][j] = sv;
      }

    // online softmax (rows owned by 16-lane tx-groups within a wave)
    float mt[4], lt[4], alpha[4];
#pragma unroll
    for (int i = 0; i < 4; ++i)
      mt[i] = fmaxf(fmaxf(s[i][0], s[i][1]), fmaxf(s[i][2], s[i][3]));
#pragma unroll
    for (int off = 1; off <= 8; off <<= 1)
#pragma unroll
      for (int i = 0; i < 4; ++i)
        mt[i] = fmaxf(mt[i], __shfl_xor(mt[i], off));
#pragma unroll
    for (int i = 0; i < 4; ++i) {
      const float mn = fmaxf(m_run[i], mt[i]);
      alpha[i] = __expf(m_run[i] - mn);  // exp(-inf)=0 on first tile
      m_run[i] = mn;
      lt[i] = 0.f;
    }
#pragma unroll
    for (int i = 0; i < 4; ++i)
#pragma unroll
      for (int j = 0; j < 4; ++j) {
        const float p = __expf(s[i][j] - m_run[i]);
        s[i][j] = p;
        lt[i] += p;
      }
#pragma unroll
    for (int off = 1; off <= 8; off <<= 1)
#pragma unroll
      for (int i = 0; i < 4; ++i)
        lt[i] += __shfl_xor(lt[i], off);
#pragma unroll
    for (int i = 0; i < 4; ++i) {
      l_run[i] = l_run[i] * alpha[i] + lt[i];
#pragma unroll
      for (int j = 0; j < 4; ++j) acc[i][j] *= alpha[i];
    }

#pragma unroll
    for (int i = 0; i < 4; ++i)
      *(float4*)&Ps[ty * 4 + i][tx * 4] = make_float4(s[i][0], s[i][1], s[i][2], s[i][3]);
    __syncthreads();

    // O += P V   (dims owned per tx)
#pragma unroll 4
    for (int c = 0; c < 64; ++c) {
      const float a0 = Ps[ty * 4 + 0][c], a1 = Ps[ty * 4 + 1][c];
      const float a2 = Ps[ty * 4 + 2][c], a3 = Ps[ty * 4 + 3][c];
      const float4 b4 = *(const float4*)&Vs[c][tx * 4];
      acc[0][0] = fmaf(a0, b4.x, acc[0][0]); acc[0][1] = fmaf(a0, b4.y, acc[0][1]);
      acc[0][2] = fmaf(a0, b4.z, acc[0][2]); acc[0][3] = fmaf(a0, b4.w, acc[0][3]);
      acc[1][0] = fmaf(a1, b4.x, acc[1][0]); acc[1][1] = fmaf(a1, b4.y, acc[1][1]);
      acc[1][2] = fmaf(a1, b4.z, acc[1][2]); acc[1][3] = fmaf(a1, b4.w, acc[1][3]);
      acc[2][0] = fmaf(a2, b4.x, acc[2][0]); acc[2][1] = fmaf(a2, b4.y, acc[2][1]);
      acc[2][2] = fmaf(a2, b4.z, acc[2][2]); acc[2][3] = fmaf(a2, b4.w, acc[2][3]);
      acc[3][0] = fmaf(a3, b4.x, acc[3][0]); acc[3][1] = fmaf(a3, b4.y, acc[3][1]);
      acc[3][2] = fmaf(a3, b4.z, acc[3][2]); acc[3][3] = fmaf(a3, b4.w, acc[3][3]);
    }
  }

  // normalize and write ctx
#pragma unroll
  for (int i = 0; i < 4; ++i) {
    const float inv = 1.f / l_run[i];
    *(float4*)&ctx[base + (size_t)(q0 + ty * 4 + i) * Dd + tx * 4] =
        make_float4(acc[i][0] * inv, acc[i][1] * inv, acc[i][2] * inv, acc[i][3] * inv);
  }
}

// ---------------------------------------------------------------------------
// out = LayerNorm(x + a) * g + b   (eps = 1e-3, one block of 128 per row)
// ---------------------------------------------------------------------------
__global__ __launch_bounds__(128) void add_ln(const float* __restrict__ x,
                                              const float* __restrict__ a,
                                              const float* __restrict__ g,
                                              const float* __restrict__ bta,
                                              float* __restrict__ out) {
  __shared__ float red[4];
  const int row = blockIdx.x;
  const int tid = threadIdx.x;
  const size_t off = (size_t)row * Dd + tid * 4;
  const float4 xv = *(const float4*)(x + off);
  const float4 av = *(const float4*)(a + off);
  float4 sv;
  sv.x = xv.x + av.x; sv.y = xv.y + av.y; sv.z = xv.z + av.z; sv.w = xv.w + av.w;
  float sum = sv.x + sv.y + sv.z + sv.w;
  float sq  = sv.x * sv.x + sv.y * sv.y + sv.z * sv.z + sv.w * sv.w;
#pragma unroll
  for (int o = 32; o >= 1; o >>= 1) {
    sum += __shfl_down(sum, o);
    sq  += __shfl_down(sq, o);
  }
  if ((tid & 63) == 0) { red[(tid >> 6) * 2] = sum; red[(tid >> 6) * 2 + 1] = sq; }
  __syncthreads();
  const float tot = red[0] + red[2];
  const float tsq = red[1] + red[3];
  const float invD = 1.f / 512.f;
  const float mean = tot * invD;
  const float var  = tsq * invD - mean * mean;
  const float rs   = rsqrtf(var + 1e-3f);
  const float4 gv = *(const float4*)(g + tid * 4);
  const float4 bv = *(const float4*)(bta + tid * 4);
  float4 ov;
  ov.x = (sv.x - mean) * rs * gv.x + bv.x;
  ov.y = (sv.y - mean) * rs * gv.y + bv.y;
  ov.z = (sv.z - mean) * rs * gv.z + bv.z;
  ov.w = (sv.w - mean) * rs * gv.w + bv.w;
  *(float4*)(out + off) = ov;
}

// ---------------------------------------------------------------------------
extern "C" void kernel_launch(void* const* d_in, const int* in_sizes, int n_in,
                              void* d_out, int out_size, void* d_ws, size_t ws_size,
                              hipStream_t stream) {
  (void)in_sizes; (void)n_in; (void)out_size; (void)ws_size;
  const float* x   = (const float*)d_in[0];
  // d_in[1] = mask: causal triu, applied analytically in flash_attn
  const float* wq  = (const float*)d_in[2];
  const float* bq  = (const float*)d_in[3];
  const float* wk  = (const float*)d_in[4];
  const float* bk  = (const float*)d_in[5];
  const float* wv  = (const float*)d_in[6];
  const float* bvp = (const float*)d_in[7];
  const float* wo  = (const float*)d_in[8];
  const float* bo  = (const float*)d_in[9];
  const float* g1  = (const float*)d_in[10];
  const float* be1 = (const float*)d_in[11];
  const float* w1  = (const float*)d_in[12];
  const float* b1  = (const float*)d_in[13];
  const float* w2  = (const float*)d_in[14];
  const float* b2  = (const float*)d_in[15];
  const float* g2  = (const float*)d_in[16];
  const float* be2 = (const float*)d_in[17];
  float* out = (float*)d_out;

  float* ws = (float*)d_ws;
  const size_t SZ = (size_t)Mm * Dd;  // 4,194,304 floats
  float* q    = ws;
  float* kbuf = ws + SZ;
  float* vbuf = ws + 2 * SZ;
  float* ctx  = ws + 3 * SZ;
  float* y    = ws + 4 * SZ;
  float* ffn1 = ws + 5 * SZ;          // 4*SZ floats (8192 x 2048)
  float* attn_out = q;                // q dead after flash_attn
  float* ffn2     = kbuf;             // k dead after flash_attn

  const dim3 blk(256);
  gemm_bias<false><<<dim3(4, 64), blk, 0, stream>>>(x, wq, bq, q, Mm, Dd, Dd);
  gemm_bias<false><<<dim3(4, 64), blk, 0, stream>>>(x, wk, bk, kbuf, Mm, Dd, Dd);
  gemm_bias<false><<<dim3(4, 64), blk, 0, stream>>>(x, wv, bvp, vbuf, Mm, Dd, Dd);
  flash_attn<<<dim3(64, 16), blk, 0, stream>>>(q, kbuf, vbuf, ctx);
  gemm_bias<false><<<dim3(4, 64), blk, 0, stream>>>(ctx, wo, bo, attn_out, Mm, Dd, Dd);
  add_ln<<<dim3(8192), dim3(128), 0, stream>>>(x, attn_out, g1, be1, y);
  gemm_bias<true ><<<dim3(16, 64), blk, 0, stream>>>(y, w1, b1, ffn1, Mm, Ff, Dd);
  gemm_bias<false><<<dim3(4, 64), blk, 0, stream>>>(ffn1, w2, b2, ffn2, Mm, Dd, Ff);
  add_ln<<<dim3(8192), dim3(128), 0, stream>>>(y, ffn2, g2, be2, out);
}

// Round 3
// 1163.127 us; speedup vs baseline: 1.6391x; 1.6391x over previous
//
#include <hip/hip_runtime.h>
#include <hip/hip_bf16.h>
#include <math.h>

#define Bb 2
#define Ss 4096
#define Dd 512
#define Hh 8
#define DHh 64
#define Ff 2048
#define Mm 8192   // Bb*Ss

typedef float  f32x4  __attribute__((ext_vector_type(4)));
typedef short  bf16x8 __attribute__((ext_vector_type(8)));

__device__ __forceinline__ ushort f2bf(float f) {
  union { float f; uint u; } c; c.f = f;
  uint u = c.u;
  uint r = (u + 0x7fffu + ((u >> 16) & 1u)) >> 16;  // RNE
  return (ushort)r;
}

// ---------------------------------------------------------------------------
// Generic fp32 GEMM: C[M,N] = A[M,K] @ W[K,N] + bias[N], optional ReLU.
// 128x128 block tile, BK=16, 256 threads, 8x8 per thread (split 4+4 rows/cols).
// ---------------------------------------------------------------------------
template<bool RELU>
__global__ __launch_bounds__(256) void gemm_bias(const float* __restrict__ A,
                                                 const float* __restrict__ W,
                                                 const float* __restrict__ bias,
                                                 float* __restrict__ C,
                                                 int M, int N, int K) {
  __shared__ __align__(16) float As[16][128];
  __shared__ __align__(16) float Ws[16][128];
  const int tid = threadIdx.x;
  const int bm = blockIdx.y * 128, bn = blockIdx.x * 128;
  const int tx = tid & 15, ty = tid >> 4;
  const int ar = tid >> 2, ac = (tid & 3) << 2;
  const int wr = tid >> 5, wc = (tid & 31) << 2;
  float acc[8][8] = {};
  const float* Ap0 = A + (size_t)(bm + ar) * K + ac;
  const float* Ap1 = Ap0 + (size_t)64 * K;
  const float* Wp0 = W + (size_t)wr * N + bn + wc;
  const float* Wp1 = Wp0 + (size_t)8 * N;

  for (int k0 = 0; k0 < K; k0 += 16) {
    float4 a0 = *(const float4*)(Ap0 + k0);
    float4 a1 = *(const float4*)(Ap1 + k0);
    float4 w0 = *(const float4*)(Wp0 + (size_t)k0 * N);
    float4 w1 = *(const float4*)(Wp1 + (size_t)k0 * N);
    __syncthreads();
    As[ac + 0][ar] = a0.x; As[ac + 1][ar] = a0.y;
    As[ac + 2][ar] = a0.z; As[ac + 3][ar] = a0.w;
    As[ac + 0][64 + ar] = a1.x; As[ac + 1][64 + ar] = a1.y;
    As[ac + 2][64 + ar] = a1.z; As[ac + 3][64 + ar] = a1.w;
    *(float4*)&Ws[wr][wc] = w0;
    *(float4*)&Ws[wr + 8][wc] = w1;
    __syncthreads();
#pragma unroll
    for (int kk = 0; kk < 16; ++kk) {
      float av[8], bv[8];
      *(float4*)&av[0] = *(const float4*)&As[kk][ty * 4];
      *(float4*)&av[4] = *(const float4*)&As[kk][64 + ty * 4];
      *(float4*)&bv[0] = *(const float4*)&Ws[kk][tx * 4];
      *(float4*)&bv[4] = *(const float4*)&Ws[kk][64 + tx * 4];
#pragma unroll
      for (int i = 0; i < 8; ++i)
#pragma unroll
        for (int j = 0; j < 8; ++j)
          acc[i][j] = fmaf(av[i], bv[j], acc[i][j]);
    }
  }

  const float4 bia0 = *(const float4*)&bias[bn + tx * 4];
  const float4 bia1 = *(const float4*)&bias[bn + 64 + tx * 4];
  const float bl[8] = {bia0.x, bia0.y, bia0.z, bia0.w, bia1.x, bia1.y, bia1.z, bia1.w};
#pragma unroll
  for (int i = 0; i < 8; ++i) {
    const int row = bm + ((i < 4) ? (ty * 4 + i) : (64 + ty * 4 + i - 4));
    float o[8];
#pragma unroll
    for (int j = 0; j < 8; ++j) {
      o[j] = acc[i][j] + bl[j];
      if (RELU) o[j] = fmaxf(o[j], 0.f);
    }
    *(float4*)&C[(size_t)row * N + bn + tx * 4]      = make_float4(o[0], o[1], o[2], o[3]);
    *(float4*)&C[(size_t)row * N + bn + 64 + tx * 4] = make_float4(o[4], o[5], o[6], o[7]);
  }
}

// ---------------------------------------------------------------------------
// Causal flash attention with bf16 MFMA (16x16x32).
// Block = 256 threads = 4 waves. Q-tile = 64 rows (16/wave, in registers).
// KV-tile = 64, staged in LDS as bf16: Ks[key][dim], Vt[dim][key] (stride 72).
// MFMA layouts (m89/m91-verified): C/D col=lane&15,row=(lane>>4)*4+reg;
// A/B: lane&15 = m/n index, k = (lane>>4)*8 + j (8 contiguous k per lane).
// ---------------------------------------------------------------------------
__global__ __launch_bounds__(256) void flash_attn_mfma(const float* __restrict__ q,
                                                       const float* __restrict__ k,
                                                       const float* __restrict__ v,
                                                       float* __restrict__ ctx) {
  __shared__ __align__(16) ushort Ks[64][72];
  __shared__ __align__(16) ushort Vt[64][72];
  __shared__ __align__(16) ushort Ps[4][16][72];

  const int t = threadIdx.x;
  const int w = t >> 6, lane = t & 63;
  const int lrow = lane & 15, lhi = lane >> 4;
  const int qt = blockIdx.x, bh = blockIdx.y;
  const int bb = bh >> 3, hh = bh & 7;
  const int q0 = qt * 64;
  const size_t base = (size_t)bb * Ss * Dd + hh * 64;

  // staging maps
  const int kkey = t >> 2, kdg = (t & 3) * 16;        // K: 1 key, 16 dims
  const int vkp = (t & 31) * 2, vdg = (t >> 5) * 8;   // V: 2 keys, 8 dims

  // Q fragments (A operand), loaded once: row = lane&15 of this wave's strip
  bf16x8 qa[2];
  {
    const float* qsrc = q + base + (size_t)(q0 + w * 16 + lrow) * Dd;
#pragma unroll
    for (int kk = 0; kk < 2; ++kk) {
      const int d0 = kk * 32 + lhi * 8;
      float4 x0 = *(const float4*)(qsrc + d0);
      float4 x1 = *(const float4*)(qsrc + d0 + 4);
      bf16x8 f;
      f[0] = (short)f2bf(x0.x); f[1] = (short)f2bf(x0.y);
      f[2] = (short)f2bf(x0.z); f[3] = (short)f2bf(x0.w);
      f[4] = (short)f2bf(x1.x); f[5] = (short)f2bf(x1.y);
      f[6] = (short)f2bf(x1.z); f[7] = (short)f2bf(x1.w);
      qa[kk] = f;
    }
  }

  float m_run[4], l_run[4];
  f32x4 oacc[4];
#pragma unroll
  for (int r = 0; r < 4; ++r) { m_run[r] = -INFINITY; l_run[r] = 0.f; }
#pragma unroll
  for (int g = 0; g < 4; ++g) oacc[g] = (f32x4)(0.f);

  for (int kt = 0; kt <= qt; ++kt) {
    const int j0 = kt * 64;

    // ---- stage K (row-major bf16) and V (transposed bf16) ----
    {
      const float* ksrc = k + base + (size_t)(j0 + kkey) * Dd + kdg;
      float4 f0 = *(const float4*)(ksrc + 0);
      float4 f1 = *(const float4*)(ksrc + 4);
      float4 f2 = *(const float4*)(ksrc + 8);
      float4 f3 = *(const float4*)(ksrc + 12);
      const float* v0p = v + base + (size_t)(j0 + vkp) * Dd + vdg;
      const float* v1p = v0p + Dd;
      float4 a0 = *(const float4*)(v0p + 0);
      float4 a1 = *(const float4*)(v0p + 4);
      float4 b0 = *(const float4*)(v1p + 0);
      float4 b1 = *(const float4*)(v1p + 4);
      __syncthreads();  // previous tile's LDS reads complete
      bf16x8 kv0, kv1;
      kv0[0] = (short)f2bf(f0.x); kv0[1] = (short)f2bf(f0.y);
      kv0[2] = (short)f2bf(f0.z); kv0[3] = (short)f2bf(f0.w);
      kv0[4] = (short)f2bf(f1.x); kv0[5] = (short)f2bf(f1.y);
      kv0[6] = (short)f2bf(f1.z); kv0[7] = (short)f2bf(f1.w);
      kv1[0] = (short)f2bf(f2.x); kv1[1] = (short)f2bf(f2.y);
      kv1[2] = (short)f2bf(f2.z); kv1[3] = (short)f2bf(f2.w);
      kv1[4] = (short)f2bf(f3.x); kv1[5] = (short)f2bf(f3.y);
      kv1[6] = (short)f2bf(f3.z); kv1[7] = (short)f2bf(f3.w);
      *(bf16x8*)&Ks[kkey][kdg]     = kv0;
      *(bf16x8*)&Ks[kkey][kdg + 8] = kv1;
      // Vt[dim][kp..kp+1] packed pairs -> conflict-free b32 writes
      const float av[8] = {a0.x, a0.y, a0.z, a0.w, a1.x, a1.y, a1.z, a1.w};
      const float bv[8] = {b0.x, b0.y, b0.z, b0.w, b1.x, b1.y, b1.z, b1.w};
#pragma unroll
      for (int i = 0; i < 8; ++i) {
        uint pk = (uint)f2bf(av[i]) | ((uint)f2bf(bv[i]) << 16);
        *(uint*)&Vt[vdg + i][vkp] = pk;
      }
      __syncthreads();
    }

    // ---- S = Q K^T ----
    f32x4 sacc[4];
#pragma unroll
    for (int g = 0; g < 4; ++g) sacc[g] = (f32x4)(0.f);
#pragma unroll
    for (int g = 0; g < 4; ++g)
#pragma unroll
      for (int kk = 0; kk < 2; ++kk) {
        bf16x8 kb = *(const bf16x8*)&Ks[g * 16 + lrow][kk * 32 + lhi * 8];
        sacc[g] = __builtin_amdgcn_mfma_f32_16x16x32_bf16(qa[kk], kb, sacc[g], 0, 0, 0);
      }

    // ---- scale + causal mask ----
    float sv[4][4];
    const bool diag = (kt == qt);
    const int qrow_base = q0 + w * 16 + lhi * 4;   // + r
    const int kcol_base = j0 + lrow;               // + g*16
#pragma unroll
    for (int g = 0; g < 4; ++g)
#pragma unroll
      for (int r = 0; r < 4; ++r) {
        float s = sacc[g][r] * 0.125f;
        if (diag && (kcol_base + g * 16) > (qrow_base + r)) s = -1e9f;
        sv[g][r] = s;
      }

    // ---- online softmax (rows live in 16-lane groups) ----
    float mt[4], lt[4], alpha[4];
#pragma unroll
    for (int r = 0; r < 4; ++r)
      mt[r] = fmaxf(fmaxf(sv[0][r], sv[1][r]), fmaxf(sv[2][r], sv[3][r]));
#pragma unroll
    for (int off = 1; off <= 8; off <<= 1)
#pragma unroll
      for (int r = 0; r < 4; ++r)
        mt[r] = fmaxf(mt[r], __shfl_xor(mt[r], off));
#pragma unroll
    for (int r = 0; r < 4; ++r) {
      const float mn = fmaxf(m_run[r], mt[r]);
      alpha[r] = __expf(m_run[r] - mn);
      m_run[r] = mn;
      lt[r] = 0.f;
    }
#pragma unroll
    for (int g = 0; g < 4; ++g)
#pragma unroll
      for (int r = 0; r < 4; ++r) {
        const float p = __expf(sv[g][r] - m_run[r]);
        sv[g][r] = p;
        lt[r] += p;
      }
#pragma unroll
    for (int off = 1; off <= 8; off <<= 1)
#pragma unroll
      for (int r = 0; r < 4; ++r)
        lt[r] += __shfl_xor(lt[r], off);
#pragma unroll
    for (int r = 0; r < 4; ++r) {
      l_run[r] = l_run[r] * alpha[r] + lt[r];
#pragma unroll
      for (int g = 0; g < 4; ++g) oacc[g][r] *= alpha[r];
    }

    // ---- P -> per-wave LDS (redistribute rows for PV A-operand) ----
#pragma unroll
    for (int g = 0; g < 4; ++g)
#pragma unroll
      for (int r = 0; r < 4; ++r)
        Ps[w][lhi * 4 + r][g * 16 + lrow] = f2bf(sv[g][r]);
    // wave-local RAW: compiler inserts lgkmcnt wait; no cross-wave dep.

    // ---- O += P V ----
    bf16x8 pa[2];
#pragma unroll
    for (int kk = 0; kk < 2; ++kk)
      pa[kk] = *(const bf16x8*)&Ps[w][lrow][kk * 32 + lhi * 8];
#pragma unroll
    for (int g = 0; g < 4; ++g)
#pragma unroll
      for (int kk = 0; kk < 2; ++kk) {
        bf16x8 vb = *(const bf16x8*)&Vt[g * 16 + lrow][kk * 32 + lhi * 8];
        oacc[g] = __builtin_amdgcn_mfma_f32_16x16x32_bf16(pa[kk], vb, oacc[g], 0, 0, 0);
      }
  }

  // ---- normalize + write ----
#pragma unroll
  for (int r = 0; r < 4; ++r) {
    const float inv = 1.f / l_run[r];
    float* dst = ctx + base + (size_t)(q0 + w * 16 + lhi * 4 + r) * Dd;
#pragma unroll
    for (int g = 0; g < 4; ++g)
      dst[g * 16 + lrow] = oacc[g][r] * inv;
  }
}

// ---------------------------------------------------------------------------
// out = LayerNorm(x + a) * g + b   (eps = 1e-3, one block of 128 per row)
// ---------------------------------------------------------------------------
__global__ __launch_bounds__(128) void add_ln(const float* __restrict__ x,
                                              const float* __restrict__ a,
                                              const float* __restrict__ g,
                                              const float* __restrict__ bta,
                                              float* __restrict__ out) {
  __shared__ float red[4];
  const int row = blockIdx.x;
  const int tid = threadIdx.x;
  const size_t off = (size_t)row * Dd + tid * 4;
  const float4 xv = *(const float4*)(x + off);
  const float4 av = *(const float4*)(a + off);
  float4 sv;
  sv.x = xv.x + av.x; sv.y = xv.y + av.y; sv.z = xv.z + av.z; sv.w = xv.w + av.w;
  float sum = sv.x + sv.y + sv.z + sv.w;
  float sq  = sv.x * sv.x + sv.y * sv.y + sv.z * sv.z + sv.w * sv.w;
#pragma unroll
  for (int o = 32; o >= 1; o >>= 1) {
    sum += __shfl_down(sum, o);
    sq  += __shfl_down(sq, o);
  }
  if ((tid & 63) == 0) { red[(tid >> 6) * 2] = sum; red[(tid >> 6) * 2 + 1] = sq; }
  __syncthreads();
  const float tot = red[0] + red[2];
  const float tsq = red[1] + red[3];
  const float invD = 1.f / 512.f;
  const float mean = tot * invD;
  const float var  = tsq * invD - mean * mean;
  const float rs   = rsqrtf(var + 1e-3f);
  const float4 gv = *(const float4*)(g + tid * 4);
  const float4 bv = *(const float4*)(bta + tid * 4);
  float4 ov;
  ov.x = (sv.x - mean) * rs * gv.x + bv.x;
  ov.y = (sv.y - mean) * rs * gv.y + bv.y;
  ov.z = (sv.z - mean) * rs * gv.z + bv.z;
  ov.w = (sv.w - mean) * rs * gv.w + bv.w;
  *(float4*)(out + off) = ov;
}

// ---------------------------------------------------------------------------
extern "C" void kernel_launch(void* const* d_in, const int* in_sizes, int n_in,
                              void* d_out, int out_size, void* d_ws, size_t ws_size,
                              hipStream_t stream) {
  (void)in_sizes; (void)n_in; (void)out_size; (void)ws_size;
  const float* x   = (const float*)d_in[0];
  // d_in[1] = mask: causal triu, applied analytically in flash_attn_mfma
  const float* wq  = (const float*)d_in[2];
  const float* bq  = (const float*)d_in[3];
  const float* wk  = (const float*)d_in[4];
  const float* bk  = (const float*)d_in[5];
  const float* wv  = (const float*)d_in[6];
  const float* bvp = (const float*)d_in[7];
  const float* wo  = (const float*)d_in[8];
  const float* bo  = (const float*)d_in[9];
  const float* g1  = (const float*)d_in[10];
  const float* be1 = (const float*)d_in[11];
  const float* w1  = (const float*)d_in[12];
  const float* b1  = (const float*)d_in[13];
  const float* w2  = (const float*)d_in[14];
  const float* b2  = (const float*)d_in[15];
  const float* g2  = (const float*)d_in[16];
  const float* be2 = (const float*)d_in[17];
  float* out = (float*)d_out;

  float* ws = (float*)d_ws;
  const size_t SZ = (size_t)Mm * Dd;
  float* q    = ws;
  float* kbuf = ws + SZ;
  float* vbuf = ws + 2 * SZ;
  float* ctx  = ws + 3 * SZ;
  float* y    = ws + 4 * SZ;
  float* ffn1 = ws + 5 * SZ;
  float* attn_out = q;
  float* ffn2     = kbuf;

  const dim3 blk(256);
  gemm_bias<false><<<dim3(4, 64), blk, 0, stream>>>(x, wq, bq, q, Mm, Dd, Dd);
  gemm_bias<false><<<dim3(4, 64), blk, 0, stream>>>(x, wk, bk, kbuf, Mm, Dd, Dd);
  gemm_bias<false><<<dim3(4, 64), blk, 0, stream>>>(x, wv, bvp, vbuf, Mm, Dd, Dd);
  flash_attn_mfma<<<dim3(64, 16), blk, 0, stream>>>(q, kbuf, vbuf, ctx);
  gemm_bias<false><<<dim3(4, 64), blk, 0, stream>>>(ctx, wo, bo, attn_out, Mm, Dd, Dd);
  add_ln<<<dim3(8192), dim3(128), 0, stream>>>(x, attn_out, g1, be1, y);
  gemm_bias<true ><<<dim3(16, 64), blk, 0, stream>>>(y, w1, b1, ffn1, Mm, Ff, Dd);
  gemm_bias<false><<<dim3(4, 64), blk, 0, stream>>>(ffn1, w2, b2, ffn2, Mm, Dd, Ff);
  add_ln<<<dim3(8192), dim3(128), 0, stream>>>(y, ffn2, g2, be2, out);
}

// Round 7
// 537.660 us; speedup vs baseline: 3.5459x; 2.1633x over previous
//
#include <hip/hip_runtime.h>
#include <hip/hip_bf16.h>
#include <math.h>

#define Bb 2
#define Ss 4096
#define Dd 512
#define Hh 8
#define Ff 2048
#define Mm 8192   // Bb*Ss

typedef float  f32x4  __attribute__((ext_vector_type(4)));
typedef short  bf16x8 __attribute__((ext_vector_type(8)));

__device__ __forceinline__ ushort f2bf(float f) {
  union { float f; uint u; } c; c.f = f;
  uint u = c.u;
  uint r = (u + 0x7fffu + ((u >> 16) & 1u)) >> 16;  // RNE
  return (ushort)r;
}

// async global->LDS, 16B per lane; LDS dest is wave-uniform base + lane*16
__device__ __forceinline__ void gload_lds16(const ushort* g, ushort* l) {
  __builtin_amdgcn_global_load_lds(
      (const __attribute__((address_space(1))) void*)g,
      (__attribute__((address_space(3))) void*)l, 16, 0, 0);
}

// ---------------------------------------------------------------------------
// bf16 MFMA GEMM (m97 structure): C[M,N] = A[M,K] @ Bt[N,K]^T + bias.
// 128x128 tile, BK=32, 256 thr = 4 waves (2x2 of 64x64), 4x4 16x16 frags/wave.
// A, Bt bf16; accum fp32; out fp32 or bf16 (+optional ReLU).
// ---------------------------------------------------------------------------
template<bool OUTBF, bool RELU>
__global__ __launch_bounds__(256) void gemm_mfma(const ushort* __restrict__ A,
                                                 const ushort* __restrict__ Bt,
                                                 const float* __restrict__ bias,
                                                 void* __restrict__ Cout,
                                                 int M, int N, int K) {
  __shared__ __align__(16) ushort As[128 * 32];
  __shared__ __align__(16) ushort Bs[128 * 32];
  const int t = threadIdx.x;
  const int w = t >> 6, lane = t & 63;
  const int lrow = lane & 15, lhi = lane >> 4;
  const int bm = blockIdx.y * 128, bn = blockIdx.x * 128;
  const int wm = (w >> 1) * 64, wn = (w & 1) * 64;
  const int sr = t >> 2, sc = (t & 3) * 8;   // staging: row, 8-elem col group

  f32x4 acc[4][4];
#pragma unroll
  for (int i = 0; i < 4; ++i)
#pragma unroll
    for (int j = 0; j < 4; ++j) acc[i][j] = (f32x4)(0.f);

  const ushort* Ap = A  + (size_t)(bm + sr) * K + sc;
  const ushort* Bp = Bt + (size_t)(bn + sr) * K + sc;
  const size_t rowK64 = (size_t)64 * K;
  ushort* AsW0 = As + w * 512;          // wave-uniform LDS bases (bytes w*1024)
  ushort* AsW1 = As + 2048 + w * 512;
  ushort* BsW0 = Bs + w * 512;
  ushort* BsW1 = Bs + 2048 + w * 512;

  for (int k0 = 0; k0 < K; k0 += 32) {
    __syncthreads();                    // prev tile's reads done
    gload_lds16(Ap + k0,          AsW0);
    gload_lds16(Ap + rowK64 + k0, AsW1);
    gload_lds16(Bp + k0,          BsW0);
    gload_lds16(Bp + rowK64 + k0, BsW1);
    __syncthreads();                    // drains vmcnt -> tiles visible
    bf16x8 af[4], bfr[4];
#pragma unroll
    for (int i = 0; i < 4; ++i)
      af[i] = *(const bf16x8*)&As[(wm + i * 16 + lrow) * 32 + lhi * 8];
#pragma unroll
    for (int j = 0; j < 4; ++j)
      bfr[j] = *(const bf16x8*)&Bs[(wn + j * 16 + lrow) * 32 + lhi * 8];
#pragma unroll
    for (int i = 0; i < 4; ++i)
#pragma unroll
      for (int j = 0; j < 4; ++j)
        acc[i][j] = __builtin_amdgcn_mfma_f32_16x16x32_bf16(af[i], bfr[j], acc[i][j], 0, 0, 0);
  }

  float bvs[4];
#pragma unroll
  for (int j = 0; j < 4; ++j) bvs[j] = bias[bn + wn + j * 16 + lrow];

#pragma unroll
  for (int i = 0; i < 4; ++i)
#pragma unroll
    for (int r = 0; r < 4; ++r) {
      const int row = bm + wm + i * 16 + lhi * 4 + r;
#pragma unroll
      for (int j = 0; j < 4; ++j) {
        float val = acc[i][j][r] + bvs[j];
        if (RELU) val = fmaxf(val, 0.f);
        const size_t idx = (size_t)row * N + bn + wn + j * 16 + lrow;
        if (OUTBF) ((ushort*)Cout)[idx] = f2bf(val);
        else       ((float*)Cout)[idx]  = val;
      }
    }
}

// ---------------------------------------------------------------------------
// Causal flash attention, bf16 in/out, bf16 MFMA 16x16x32 (round-3 verified).
// ---------------------------------------------------------------------------
__global__ __launch_bounds__(256) void flash_attn_mfma(const ushort* __restrict__ q,
                                                       const ushort* __restrict__ k,
                                                       const ushort* __restrict__ v,
                                                       ushort* __restrict__ ctx) {
  __shared__ __align__(16) ushort Ks[64][72];
  __shared__ __align__(16) ushort Vt[64][72];
  __shared__ __align__(16) ushort Ps[4][16][72];

  const int t = threadIdx.x;
  const int w = t >> 6, lane = t & 63;
  const int lrow = lane & 15, lhi = lane >> 4;
  const int qt = blockIdx.x, bh = blockIdx.y;
  const int bb = bh >> 3, hh = bh & 7;
  const int q0 = qt * 64;
  const size_t base = (size_t)bb * Ss * Dd + hh * 64;

  const int kkey = t >> 2, kdg = (t & 3) * 16;
  const int vkp = (t & 31) * 2, vdg = (t >> 5) * 8;

  bf16x8 qa[2];
  {
    const ushort* qsrc = q + base + (size_t)(q0 + w * 16 + lrow) * Dd;
    qa[0] = *(const bf16x8*)(qsrc + lhi * 8);
    qa[1] = *(const bf16x8*)(qsrc + 32 + lhi * 8);
  }

  float m_run[4], l_run[4];
  f32x4 oacc[4];
#pragma unroll
  for (int r = 0; r < 4; ++r) { m_run[r] = -INFINITY; l_run[r] = 0.f; }
#pragma unroll
  for (int g = 0; g < 4; ++g) oacc[g] = (f32x4)(0.f);

  for (int kt = 0; kt <= qt; ++kt) {
    const int j0 = kt * 64;

    {  // stage K rows + V transposed (pair-packed b32 writes)
      const ushort* ksrc = k + base + (size_t)(j0 + kkey) * Dd + kdg;
      bf16x8 k0r = *(const bf16x8*)(ksrc);
      bf16x8 k1r = *(const bf16x8*)(ksrc + 8);
      const ushort* vsrc = v + base + (size_t)(j0 + vkp) * Dd + vdg;
      bf16x8 va  = *(const bf16x8*)(vsrc);
      bf16x8 vbr = *(const bf16x8*)(vsrc + Dd);
      __syncthreads();
      *(bf16x8*)&Ks[kkey][kdg]     = k0r;
      *(bf16x8*)&Ks[kkey][kdg + 8] = k1r;
#pragma unroll
      for (int i = 0; i < 8; ++i) {
        uint pk = (uint)(ushort)va[i] | ((uint)(ushort)vbr[i] << 16);
        *(uint*)&Vt[vdg + i][vkp] = pk;
      }
      __syncthreads();
    }

    // ---- S = Q K^T ----
    f32x4 sacc[4];
#pragma unroll
    for (int g = 0; g < 4; ++g) sacc[g] = (f32x4)(0.f);
#pragma unroll
    for (int g = 0; g < 4; ++g)
#pragma unroll
      for (int kk = 0; kk < 2; ++kk) {
        bf16x8 kb = *(const bf16x8*)&Ks[g * 16 + lrow][kk * 32 + lhi * 8];
        sacc[g] = __builtin_amdgcn_mfma_f32_16x16x32_bf16(qa[kk], kb, sacc[g], 0, 0, 0);
      }

    // ---- scale + causal mask ----
    float sv[4][4];
    const bool diag = (kt == qt);
    const int qrow_base = q0 + w * 16 + lhi * 4;
    const int kcol_base = j0 + lrow;
#pragma unroll
    for (int g = 0; g < 4; ++g)
#pragma unroll
      for (int r = 0; r < 4; ++r) {
        float s = sacc[g][r] * 0.125f;
        if (diag && (kcol_base + g * 16) > (qrow_base + r)) s = -1e9f;
        sv[g][r] = s;
      }

    // ---- online softmax ----
    float mt[4], lt[4], alpha[4];
#pragma unroll
    for (int r = 0; r < 4; ++r)
      mt[r] = fmaxf(fmaxf(sv[0][r], sv[1][r]), fmaxf(sv[2][r], sv[3][r]));
#pragma unroll
    for (int off = 1; off <= 8; off <<= 1)
#pragma unroll
      for (int r = 0; r < 4; ++r)
        mt[r] = fmaxf(mt[r], __shfl_xor(mt[r], off));
#pragma unroll
    for (int r = 0; r < 4; ++r) {
      const float mn = fmaxf(m_run[r], mt[r]);
      alpha[r] = __expf(m_run[r] - mn);
      m_run[r] = mn;
      lt[r] = 0.f;
    }
#pragma unroll
    for (int g = 0; g < 4; ++g)
#pragma unroll
      for (int r = 0; r < 4; ++r) {
        const float p = __expf(sv[g][r] - m_run[r]);
        sv[g][r] = p;
        lt[r] += p;
      }
#pragma unroll
    for (int off = 1; off <= 8; off <<= 1)
#pragma unroll
      for (int r = 0; r < 4; ++r)
        lt[r] += __shfl_xor(lt[r], off);
#pragma unroll
    for (int r = 0; r < 4; ++r) {
      l_run[r] = l_run[r] * alpha[r] + lt[r];
#pragma unroll
      for (int g = 0; g < 4; ++g) oacc[g][r] *= alpha[r];
    }

    // ---- P -> per-wave LDS ----
#pragma unroll
    for (int g = 0; g < 4; ++g)
#pragma unroll
      for (int r = 0; r < 4; ++r)
        Ps[w][lhi * 4 + r][g * 16 + lrow] = f2bf(sv[g][r]);

    // ---- O += P V ----
    bf16x8 pa[2];
#pragma unroll
    for (int kk = 0; kk < 2; ++kk)
      pa[kk] = *(const bf16x8*)&Ps[w][lrow][kk * 32 + lhi * 8];
#pragma unroll
    for (int g = 0; g < 4; ++g)
#pragma unroll
      for (int kk = 0; kk < 2; ++kk) {
        bf16x8 vb = *(const bf16x8*)&Vt[g * 16 + lrow][kk * 32 + lhi * 8];
        oacc[g] = __builtin_amdgcn_mfma_f32_16x16x32_bf16(pa[kk], vb, oacc[g], 0, 0, 0);
      }
  }

  // ---- normalize + write bf16 ----
#pragma unroll
  for (int r = 0; r < 4; ++r) {
    const float inv = 1.f / l_run[r];
    ushort* dst = ctx + base + (size_t)(q0 + w * 16 + lhi * 4 + r) * Dd;
#pragma unroll
    for (int g = 0; g < 4; ++g)
      dst[g * 16 + lrow] = f2bf(oacc[g][r] * inv);
  }
}

// ---------------------------------------------------------------------------
// out = LayerNorm(x + a) * g + b (fp32); optionally also bf16 copy.
// ---------------------------------------------------------------------------
template<bool WB>
__global__ __launch_bounds__(128) void add_ln(const float* __restrict__ x,
                                              const float* __restrict__ a,
                                              const float* __restrict__ g,
                                              const float* __restrict__ bta,
                                              float* __restrict__ out,
                                              ushort* __restrict__ outb) {
  __shared__ float red[4];
  const int row = blockIdx.x;
  const int tid = threadIdx.x;
  const size_t off = (size_t)row * Dd + tid * 4;
  const float4 xv = *(const float4*)(x + off);
  const float4 av = *(const float4*)(a + off);
  float4 sv;
  sv.x = xv.x + av.x; sv.y = xv.y + av.y; sv.z = xv.z + av.z; sv.w = xv.w + av.w;
  float sum = sv.x + sv.y + sv.z + sv.w;
  float sq  = sv.x * sv.x + sv.y * sv.y + sv.z * sv.z + sv.w * sv.w;
#pragma unroll
  for (int o = 32; o >= 1; o >>= 1) {
    sum += __shfl_down(sum, o);
    sq  += __shfl_down(sq, o);
  }
  if ((tid & 63) == 0) { red[(tid >> 6) * 2] = sum; red[(tid >> 6) * 2 + 1] = sq; }
  __syncthreads();
  const float tot = red[0] + red[2];
  const float tsq = red[1] + red[3];
  const float invD = 1.f / 512.f;
  const float mean = tot * invD;
  const float var  = tsq * invD - mean * mean;
  const float rs   = rsqrtf(var + 1e-3f);
  const float4 gv = *(const float4*)(g + tid * 4);
  const float4 bv = *(const float4*)(bta + tid * 4);
  float4 ov;
  ov.x = (sv.x - mean) * rs * gv.x + bv.x;
  ov.y = (sv.y - mean) * rs * gv.y + bv.y;
  ov.z = (sv.z - mean) * rs * gv.z + bv.z;
  ov.w = (sv.w - mean) * rs * gv.w + bv.w;
  *(float4*)(out + off) = ov;
  if (WB) {
    ushort4 ob = {f2bf(ov.x), f2bf(ov.y), f2bf(ov.z), f2bf(ov.w)};
    *(ushort4*)(outb + off) = ob;
  }
}

// ---------------------------------------------------------------------------
// prep: fp32 -> bf16 cast (x), and fp32 W[K,N] -> bf16 Wt[N,K] transpose-cast
// ---------------------------------------------------------------------------
__global__ __launch_bounds__(256) void cast_bf16(const float* __restrict__ in,
                                                 ushort* __restrict__ out, int n4) {
  const int i = blockIdx.x * 256 + threadIdx.x;
  if (i < n4) {
    const float4 vin = ((const float4*)in)[i];
    ushort4 o = {f2bf(vin.x), f2bf(vin.y), f2bf(vin.z), f2bf(vin.w)};
    ((ushort4*)out)[i] = o;
  }
}

__global__ __launch_bounds__(256) void transpose_cast(const float* __restrict__ W,
                                                      ushort* __restrict__ Wt,
                                                      int K, int N) {
  __shared__ float tile[32][33];
  const int bk = blockIdx.y * 32, bn = blockIdx.x * 32;
  const int tx = threadIdx.x & 31, ty = threadIdx.x >> 5;
#pragma unroll
  for (int i = 0; i < 32; i += 8)
    tile[ty + i][tx] = W[(size_t)(bk + ty + i) * N + bn + tx];
  __syncthreads();
#pragma unroll
  for (int i = 0; i < 32; i += 8)
    Wt[(size_t)(bn + ty + i) * K + bk + tx] = f2bf(tile[tx][ty + i]);
}

// ---------------------------------------------------------------------------
extern "C" void kernel_launch(void* const* d_in, const int* in_sizes, int n_in,
                              void* d_out, int out_size, void* d_ws, size_t ws_size,
                              hipStream_t stream) {
  (void)in_sizes; (void)n_in; (void)out_size; (void)ws_size;
  const float* x   = (const float*)d_in[0];
  // d_in[1] = mask: causal, applied analytically
  const float* wq  = (const float*)d_in[2];
  const float* bq  = (const float*)d_in[3];
  const float* wk  = (const float*)d_in[4];
  const float* bk  = (const float*)d_in[5];
  const float* wv  = (const float*)d_in[6];
  const float* bvp = (const float*)d_in[7];
  const float* wo  = (const float*)d_in[8];
  const float* bo  = (const float*)d_in[9];
  const float* g1  = (const float*)d_in[10];
  const float* be1 = (const float*)d_in[11];
  const float* w1  = (const float*)d_in[12];
  const float* b1  = (const float*)d_in[13];
  const float* w2  = (const float*)d_in[14];
  const float* b2  = (const float*)d_in[15];
  const float* g2  = (const float*)d_in[16];
  const float* be2 = (const float*)d_in[17];
  float* out = (float*)d_out;

  const size_t SZ  = (size_t)Mm * Dd;      // 4,194,304
  const size_t WSZ = (size_t)Dd * Dd;      // 262,144
  const size_t W1SZ = (size_t)Dd * Ff;     // 1,048,576

  float* fp = (float*)d_ws;
  float* attn_out = fp;                    // fp32 SZ
  float* y        = fp + SZ;               // fp32 SZ
  float* ffn2     = fp + 2 * SZ;           // fp32 SZ
  ushort* ub   = (ushort*)(fp + 3 * SZ);
  ushort* xb    = ub;                      // SZ
  ushort* qb    = ub + SZ;
  ushort* kbb   = ub + 2 * SZ;
  ushort* vbb   = ub + 3 * SZ;
  ushort* ctxb  = ub + 4 * SZ;
  ushort* yb    = ub + 5 * SZ;
  ushort* ffn1b = ub + 6 * SZ;             // 4*SZ (8192 x 2048)
  ushort* wqt   = ub + 10 * SZ;
  ushort* wkt   = wqt + WSZ;
  ushort* wvt   = wkt + WSZ;
  ushort* wot   = wvt + WSZ;
  ushort* w1t   = wot + WSZ;               // [2048,512]
  ushort* w2t   = w1t + W1SZ;              // [512,2048]

  // prep
  cast_bf16<<<dim3((int)(SZ / 4 / 256)), dim3(256), 0, stream>>>(x, xb, (int)(SZ / 4));
  transpose_cast<<<dim3(16, 16), dim3(256), 0, stream>>>(wq, wqt, Dd, Dd);
  transpose_cast<<<dim3(16, 16), dim3(256), 0, stream>>>(wk, wkt, Dd, Dd);
  transpose_cast<<<dim3(16, 16), dim3(256), 0, stream>>>(wv, wvt, Dd, Dd);
  transpose_cast<<<dim3(16, 16), dim3(256), 0, stream>>>(wo, wot, Dd, Dd);
  transpose_cast<<<dim3(64, 16), dim3(256), 0, stream>>>(w1, w1t, Dd, Ff);
  transpose_cast<<<dim3(16, 64), dim3(256), 0, stream>>>(w2, w2t, Ff, Dd);

  const dim3 blk(256);
  // QKV
  gemm_mfma<true,  false><<<dim3(4, 64), blk, 0, stream>>>(xb, wqt, bq,  qb,  Mm, Dd, Dd);
  gemm_mfma<true,  false><<<dim3(4, 64), blk, 0, stream>>>(xb, wkt, bk,  kbb, Mm, Dd, Dd);
  gemm_mfma<true,  false><<<dim3(4, 64), blk, 0, stream>>>(xb, wvt, bvp, vbb, Mm, Dd, Dd);
  // attention
  flash_attn_mfma<<<dim3(64, 16), blk, 0, stream>>>(qb, kbb, vbb, ctxb);
  // out-proj (fp32 out for residual)
  gemm_mfma<false, false><<<dim3(4, 64), blk, 0, stream>>>(ctxb, wot, bo, attn_out, Mm, Dd, Dd);
  // LN1 (fp32 + bf16 copies)
  add_ln<true><<<dim3(8192), dim3(128), 0, stream>>>(x, attn_out, g1, be1, y, yb);
  // FFN
  gemm_mfma<true,  true ><<<dim3(16, 64), blk, 0, stream>>>(yb, w1t, b1, ffn1b, Mm, Ff, Dd);
  gemm_mfma<false, false><<<dim3(4, 64), blk, 0, stream>>>(ffn1b, w2t, b2, ffn2, Mm, Dd, Ff);
  // LN2
  add_ln<false><<<dim3(8192), dim3(128), 0, stream>>>(y, ffn2, g2, be2, out, (ushort*)nullptr);
}

// Round 9
// 504.420 us; speedup vs baseline: 3.7795x; 1.0659x over previous
//
#include <hip/hip_runtime.h>
#include <hip/hip_bf16.h>
#include <math.h>

#define Bb 2
#define Ss 4096
#define Dd 512
#define Hh 8
#define Ff 2048
#define Mm 8192   // Bb*Ss
#define QT3 1536  // 3*Dd, merged qkv row stride

typedef float  f32x4  __attribute__((ext_vector_type(4)));
typedef short  bf16x8 __attribute__((ext_vector_type(8)));

__device__ __forceinline__ ushort f2bf(float f) {
  union { float f; uint u; } c; c.f = f;
  uint u = c.u;
  uint r = (u + 0x7fffu + ((u >> 16) & 1u)) >> 16;  // RNE
  return (ushort)r;
}

// async global->LDS, 16B per lane; LDS dest is wave-uniform base + lane*16
__device__ __forceinline__ void gload_lds16(const ushort* g, ushort* l) {
  __builtin_amdgcn_global_load_lds(
      (const __attribute__((address_space(1))) void*)g,
      (__attribute__((address_space(3))) void*)l, 16, 0, 0);
}

// ---------------------------------------------------------------------------
// bf16 MFMA GEMM (m97 structure): C[M,N] = A[M,K] @ Bt[N,K]^T + bias.
// 128x128 tile, BK=32, 256 thr = 4 waves (2x2 of 64x64), 4x4 16x16 frags/wave.
// ---------------------------------------------------------------------------
template<bool OUTBF, bool RELU>
__global__ __launch_bounds__(256) void gemm_mfma(const ushort* __restrict__ A,
                                                 const ushort* __restrict__ Bt,
                                                 const float* __restrict__ bias,
                                                 void* __restrict__ Cout,
                                                 int M, int N, int K) {
  __shared__ __align__(16) ushort As[128 * 32];
  __shared__ __align__(16) ushort Bs[128 * 32];
  const int t = threadIdx.x;
  const int w = t >> 6, lane = t & 63;
  const int lrow = lane & 15, lhi = lane >> 4;
  const int bm = blockIdx.y * 128, bn = blockIdx.x * 128;
  const int wm = (w >> 1) * 64, wn = (w & 1) * 64;
  const int sr = t >> 2, sc = (t & 3) * 8;   // staging: row, 8-elem col group

  f32x4 acc[4][4];
#pragma unroll
  for (int i = 0; i < 4; ++i)
#pragma unroll
    for (int j = 0; j < 4; ++j) acc[i][j] = (f32x4)(0.f);

  const ushort* Ap = A  + (size_t)(bm + sr) * K + sc;
  const ushort* Bp = Bt + (size_t)(bn + sr) * K + sc;
  const size_t rowK64 = (size_t)64 * K;
  ushort* AsW0 = As + w * 512;          // wave-uniform LDS bases
  ushort* AsW1 = As + 2048 + w * 512;
  ushort* BsW0 = Bs + w * 512;
  ushort* BsW1 = Bs + 2048 + w * 512;

  for (int k0 = 0; k0 < K; k0 += 32) {
    __syncthreads();
    gload_lds16(Ap + k0,          AsW0);
    gload_lds16(Ap + rowK64 + k0, AsW1);
    gload_lds16(Bp + k0,          BsW0);
    gload_lds16(Bp + rowK64 + k0, BsW1);
    __syncthreads();
    bf16x8 af[4], bfr[4];
#pragma unroll
    for (int i = 0; i < 4; ++i)
      af[i] = *(const bf16x8*)&As[(wm + i * 16 + lrow) * 32 + lhi * 8];
#pragma unroll
    for (int j = 0; j < 4; ++j)
      bfr[j] = *(const bf16x8*)&Bs[(wn + j * 16 + lrow) * 32 + lhi * 8];
#pragma unroll
    for (int i = 0; i < 4; ++i)
#pragma unroll
      for (int j = 0; j < 4; ++j)
        acc[i][j] = __builtin_amdgcn_mfma_f32_16x16x32_bf16(af[i], bfr[j], acc[i][j], 0, 0, 0);
  }

  float bvs[4];
#pragma unroll
  for (int j = 0; j < 4; ++j) bvs[j] = bias[bn + wn + j * 16 + lrow];

#pragma unroll
  for (int i = 0; i < 4; ++i)
#pragma unroll
    for (int r = 0; r < 4; ++r) {
      const int row = bm + wm + i * 16 + lhi * 4 + r;
#pragma unroll
      for (int j = 0; j < 4; ++j) {
        float val = acc[i][j][r] + bvs[j];
        if (RELU) val = fmaxf(val, 0.f);
        const size_t idx = (size_t)row * N + bn + wn + j * 16 + lrow;
        if (OUTBF) ((ushort*)Cout)[idx] = f2bf(val);
        else       ((float*)Cout)[idx]  = val;
      }
    }
}

// ---------------------------------------------------------------------------
// Causal flash attention v2: QTILE=128 (4 waves x 32 rows), KV=64,
// async-staged K/V (register prefetch of tile t+1 under compute of tile t),
// descending-qt launch order. Input: merged qkv [Mm, 1536] bf16.
// ---------------------------------------------------------------------------
__global__ __launch_bounds__(256) void flash_attn_mfma(const ushort* __restrict__ qkv,
                                                       ushort* __restrict__ ctx) {
  __shared__ __align__(16) ushort Ks[64][72];
  __shared__ __align__(16) ushort Vt[64][72];
  __shared__ __align__(16) ushort Ps[4][32][72];

  const int t = threadIdx.x;
  const int w = t >> 6, lane = t & 63;
  const int lrow = lane & 15, lhi = lane >> 4;
  const int qt = (int)(gridDim.x - 1 - blockIdx.x);  // long blocks first
  const int bh = blockIdx.y;
  const int bb = bh >> 3, hh = bh & 7;
  const int q0 = qt * 128;
  const size_t baseq = (size_t)bb * Ss * QT3 + hh * 64;
  const ushort* qp = qkv + baseq;
  const ushort* kp = qkv + baseq + 512;
  const ushort* vp = qkv + baseq + 1024;

  const int kkey = t >> 2, kdg = (t & 3) * 16;       // K stager: 1 key, 16 dims
  const int vkp = (t & 31) * 2, vdg = (t >> 5) * 8;  // V stager: 2 keys, 8 dims

  // Q fragments: wave rows q0 + w*32 + i*16 + lrow
  bf16x8 qa[2][2];
#pragma unroll
  for (int i = 0; i < 2; ++i) {
    const ushort* qsrc = qp + (size_t)(q0 + w * 32 + i * 16 + lrow) * QT3;
    qa[i][0] = *(const bf16x8*)(qsrc + lhi * 8);
    qa[i][1] = *(const bf16x8*)(qsrc + 32 + lhi * 8);
  }

  float m_run[8], l_run[8];
  f32x4 oacc[2][4];
#pragma unroll
  for (int z = 0; z < 8; ++z) { m_run[z] = -INFINITY; l_run[z] = 0.f; }
#pragma unroll
  for (int i = 0; i < 2; ++i)
#pragma unroll
    for (int g = 0; g < 4; ++g) oacc[i][g] = (f32x4)(0.f);

  const int nt = 2 * qt + 2;

  // prologue: prefetch tile 0 into registers
  bf16x8 kr0, kr1, vr0, vr1;
  {
    const ushort* ksrc = kp + (size_t)kkey * QT3 + kdg;
    kr0 = *(const bf16x8*)(ksrc);
    kr1 = *(const bf16x8*)(ksrc + 8);
    const ushort* vsrc = vp + (size_t)vkp * QT3 + vdg;
    vr0 = *(const bf16x8*)(vsrc);
    vr1 = *(const bf16x8*)(vsrc + QT3);
  }

  for (int kt = 0; kt < nt; ++kt) {
    const int j0 = kt * 64;

    // ---- write staged regs -> LDS ----
    __syncthreads();                 // all waves done reading previous tile
    *(bf16x8*)&Ks[kkey][kdg]     = kr0;
    *(bf16x8*)&Ks[kkey][kdg + 8] = kr1;
#pragma unroll
    for (int i = 0; i < 8; ++i) {
      uint pk = (uint)(ushort)vr0[i] | ((uint)(ushort)vr1[i] << 16);
      *(uint*)&Vt[vdg + i][vkp] = pk;
    }
    __syncthreads();                 // tile visible

    // ---- issue next tile's loads (latency hidden under compute below) ----
    if (kt + 1 < nt) {
      const int jn = (kt + 1) * 64;
      const ushort* ksrc = kp + (size_t)(jn + kkey) * QT3 + kdg;
      kr0 = *(const bf16x8*)(ksrc);
      kr1 = *(const bf16x8*)(ksrc + 8);
      const ushort* vsrc = vp + (size_t)(jn + vkp) * QT3 + vdg;
      vr0 = *(const bf16x8*)(vsrc);
      vr1 = *(const bf16x8*)(vsrc + QT3);
    }

    // ---- S = Q K^T ----
    f32x4 sacc[2][4];
#pragma unroll
    for (int i = 0; i < 2; ++i)
#pragma unroll
      for (int g = 0; g < 4; ++g) sacc[i][g] = (f32x4)(0.f);
#pragma unroll
    for (int g = 0; g < 4; ++g)
#pragma unroll
      for (int kk = 0; kk < 2; ++kk) {
        bf16x8 kb = *(const bf16x8*)&Ks[g * 16 + lrow][kk * 32 + lhi * 8];
#pragma unroll
        for (int i = 0; i < 2; ++i)
          sacc[i][g] = __builtin_amdgcn_mfma_f32_16x16x32_bf16(qa[i][kk], kb, sacc[i][g], 0, 0, 0);
      }

    // ---- scale + causal mask ----
    float sv[2][4][4];
    const bool diag = (j0 + 63 > q0);
#pragma unroll
    for (int i = 0; i < 2; ++i)
#pragma unroll
      for (int g = 0; g < 4; ++g)
#pragma unroll
        for (int r = 0; r < 4; ++r) {
          float s = sacc[i][g][r] * 0.125f;
          if (diag) {
            const int qrow = q0 + w * 32 + i * 16 + lhi * 4 + r;
            const int kcol = j0 + g * 16 + lrow;
            if (kcol > qrow) s = -1e9f;
          }
          sv[i][g][r] = s;
        }

    // ---- online softmax (rows live in 16-lane lrow groups) ----
    float mt[8], lt[8], alpha[8];
#pragma unroll
    for (int i = 0; i < 2; ++i)
#pragma unroll
      for (int r = 0; r < 4; ++r)
        mt[i * 4 + r] = fmaxf(fmaxf(sv[i][0][r], sv[i][1][r]),
                              fmaxf(sv[i][2][r], sv[i][3][r]));
#pragma unroll
    for (int off = 1; off <= 8; off <<= 1)
#pragma unroll
      for (int z = 0; z < 8; ++z)
        mt[z] = fmaxf(mt[z], __shfl_xor(mt[z], off));
#pragma unroll
    for (int z = 0; z < 8; ++z) {
      const float mn = fmaxf(m_run[z], mt[z]);
      alpha[z] = __expf(m_run[z] - mn);
      m_run[z] = mn;
      lt[z] = 0.f;
    }
#pragma unroll
    for (int i = 0; i < 2; ++i)
#pragma unroll
      for (int g = 0; g < 4; ++g)
#pragma unroll
        for (int r = 0; r < 4; ++r) {
          const float p = __expf(sv[i][g][r] - m_run[i * 4 + r]);
          sv[i][g][r] = p;
          lt[i * 4 + r] += p;
        }
#pragma unroll
    for (int off = 1; off <= 8; off <<= 1)
#pragma unroll
      for (int z = 0; z < 8; ++z)
        lt[z] += __shfl_xor(lt[z], off);
#pragma unroll
    for (int i = 0; i < 2; ++i)
#pragma unroll
      for (int r = 0; r < 4; ++r) {
        const int z = i * 4 + r;
        l_run[z] = l_run[z] * alpha[z] + lt[z];
#pragma unroll
        for (int g = 0; g < 4; ++g) oacc[i][g][r] *= alpha[z];
      }

    // ---- P -> per-wave LDS (redistribute rows for PV A-operand) ----
#pragma unroll
    for (int i = 0; i < 2; ++i)
#pragma unroll
      for (int g = 0; g < 4; ++g)
#pragma unroll
        for (int r = 0; r < 4; ++r)
          Ps[w][i * 16 + lhi * 4 + r][g * 16 + lrow] = f2bf(sv[i][g][r]);

    // ---- O += P V ----
    bf16x8 pa[2][2];
#pragma unroll
    for (int i = 0; i < 2; ++i)
#pragma unroll
      for (int kk = 0; kk < 2; ++kk)
        pa[i][kk] = *(const bf16x8*)&Ps[w][i * 16 + lrow][kk * 32 + lhi * 8];
#pragma unroll
    for (int g = 0; g < 4; ++g)
#pragma unroll
      for (int kk = 0; kk < 2; ++kk) {
        bf16x8 vb = *(const bf16x8*)&Vt[g * 16 + lrow][kk * 32 + lhi * 8];
#pragma unroll
        for (int i = 0; i < 2; ++i)
          oacc[i][g] = __builtin_amdgcn_mfma_f32_16x16x32_bf16(pa[i][kk], vb, oacc[i][g], 0, 0, 0);
      }
  }

  // ---- normalize + write bf16 ctx [Mm, Dd] ----
  const size_t cbase = (size_t)bb * Ss * Dd + hh * 64;
#pragma unroll
  for (int i = 0; i < 2; ++i)
#pragma unroll
    for (int r = 0; r < 4; ++r) {
      const float inv = 1.f / l_run[i * 4 + r];
      ushort* dst = ctx + cbase + (size_t)(q0 + w * 32 + i * 16 + lhi * 4 + r) * Dd;
#pragma unroll
      for (int g = 0; g < 4; ++g)
        dst[g * 16 + lrow] = f2bf(oacc[i][g][r] * inv);
    }
}

// ---------------------------------------------------------------------------
// out = LayerNorm(x + a) * g + b (fp32); optionally also bf16 copy.
// ---------------------------------------------------------------------------
template<bool WB>
__global__ __launch_bounds__(128) void add_ln(const float* __restrict__ x,
                                              const float* __restrict__ a,
                                              const float* __restrict__ g,
                                              const float* __restrict__ bta,
                                              float* __restrict__ out,
                                              ushort* __restrict__ outb) {
  __shared__ float red[4];
  const int row = blockIdx.x;
  const int tid = threadIdx.x;
  const size_t off = (size_t)row * Dd + tid * 4;
  const float4 xv = *(const float4*)(x + off);
  const float4 av = *(const float4*)(a + off);
  float4 sv;
  sv.x = xv.x + av.x; sv.y = xv.y + av.y; sv.z = xv.z + av.z; sv.w = xv.w + av.w;
  float sum = sv.x + sv.y + sv.z + sv.w;
  float sq  = sv.x * sv.x + sv.y * sv.y + sv.z * sv.z + sv.w * sv.w;
#pragma unroll
  for (int o = 32; o >= 1; o >>= 1) {
    sum += __shfl_down(sum, o);
    sq  += __shfl_down(sq, o);
  }
  if ((tid & 63) == 0) { red[(tid >> 6) * 2] = sum; red[(tid >> 6) * 2 + 1] = sq; }
  __syncthreads();
  const float tot = red[0] + red[2];
  const float tsq = red[1] + red[3];
  const float invD = 1.f / 512.f;
  const float mean = tot * invD;
  const float var  = tsq * invD - mean * mean;
  const float rs   = rsqrtf(var + 1e-3f);
  const float4 gv = *(const float4*)(g + tid * 4);
  const float4 bv = *(const float4*)(bta + tid * 4);
  float4 ov;
  ov.x = (sv.x - mean) * rs * gv.x + bv.x;
  ov.y = (sv.y - mean) * rs * gv.y + bv.y;
  ov.z = (sv.z - mean) * rs * gv.z + bv.z;
  ov.w = (sv.w - mean) * rs * gv.w + bv.w;
  *(float4*)(out + off) = ov;
  if (WB) {
    ushort4 ob = {f2bf(ov.x), f2bf(ov.y), f2bf(ov.z), f2bf(ov.w)};
    *(ushort4*)(outb + off) = ob;
  }
}

// ---------------------------------------------------------------------------
// prep kernels
// ---------------------------------------------------------------------------
__global__ __launch_bounds__(256) void cast_bf16(const float* __restrict__ in,
                                                 ushort* __restrict__ out, int n4) {
  const int i = blockIdx.x * 256 + threadIdx.x;
  if (i < n4) {
    const float4 vin = ((const float4*)in)[i];
    ushort4 o = {f2bf(vin.x), f2bf(vin.y), f2bf(vin.z), f2bf(vin.w)};
    ((ushort4*)out)[i] = o;
  }
}

__global__ __launch_bounds__(256) void transpose_cast(const float* __restrict__ W,
                                                      ushort* __restrict__ Wt,
                                                      int K, int N) {
  __shared__ float tile[32][33];
  const int bk = blockIdx.y * 32, bn = blockIdx.x * 32;
  const int tx = threadIdx.x & 31, ty = threadIdx.x >> 5;
#pragma unroll
  for (int i = 0; i < 32; i += 8)
    tile[ty + i][tx] = W[(size_t)(bk + ty + i) * N + bn + tx];
  __syncthreads();
#pragma unroll
  for (int i = 0; i < 32; i += 8)
    Wt[(size_t)(bn + ty + i) * K + bk + tx] = f2bf(tile[tx][ty + i]);
}

__global__ __launch_bounds__(256) void concat3(const float* __restrict__ a,
                                               const float* __restrict__ b,
                                               const float* __restrict__ c,
                                               float* __restrict__ o) {
  const int i = blockIdx.x * 256 + threadIdx.x;  // 1536 total
  if (i < 512) o[i] = a[i];
  else if (i < 1024) o[i] = b[i - 512];
  else if (i < 1536) o[i] = c[i - 1024];
}

// ---------------------------------------------------------------------------
extern "C" void kernel_launch(void* const* d_in, const int* in_sizes, int n_in,
                              void* d_out, int out_size, void* d_ws, size_t ws_size,
                              hipStream_t stream) {
  (void)in_sizes; (void)n_in; (void)out_size; (void)ws_size;
  const float* x   = (const float*)d_in[0];
  // d_in[1] = mask: causal, applied analytically
  const float* wq  = (const float*)d_in[2];
  const float* bq  = (const float*)d_in[3];
  const float* wk  = (const float*)d_in[4];
  const float* bk  = (const float*)d_in[5];
  const float* wv  = (const float*)d_in[6];
  const float* bvp = (const float*)d_in[7];
  const float* wo  = (const float*)d_in[8];
  const float* bo  = (const float*)d_in[9];
  const float* g1  = (const float*)d_in[10];
  const float* be1 = (const float*)d_in[11];
  const float* w1  = (const float*)d_in[12];
  const float* b1  = (const float*)d_in[13];
  const float* w2  = (const float*)d_in[14];
  const float* b2  = (const float*)d_in[15];
  const float* g2  = (const float*)d_in[16];
  const float* be2 = (const float*)d_in[17];
  float* out = (float*)d_out;

  const size_t SZ  = (size_t)Mm * Dd;      // 4,194,304
  const size_t WSZ = (size_t)Dd * Dd;      // 262,144
  const size_t W1SZ = (size_t)Dd * Ff;     // 1,048,576

  float* fp = (float*)d_ws;
  float* attn_out = fp;                    // fp32 SZ
  float* y        = fp + SZ;               // fp32 SZ
  float* ffn2     = fp + 2 * SZ;           // fp32 SZ
  ushort* ub   = (ushort*)(fp + 3 * SZ);
  ushort* xb    = ub;                      // SZ
  ushort* qkvb  = ub + SZ;                 // 3*SZ  (8192 x 1536)
  ushort* ctxb  = ub + 4 * SZ;             // SZ
  ushort* yb    = ub + 5 * SZ;             // SZ
  ushort* ffn1b = ub + 6 * SZ;             // 4*SZ  (8192 x 2048)
  ushort* wqkvt = ub + 10 * SZ;            // 3*WSZ: [1536,512] = wq^T|wk^T|wv^T
  ushort* wkt   = wqkvt + WSZ;
  ushort* wvt   = wkt + WSZ;
  ushort* wot   = wqkvt + 3 * WSZ;         // WSZ
  ushort* w1t   = wot + WSZ;               // W1SZ [2048,512]
  ushort* w2t   = w1t + W1SZ;              // W1SZ [512,2048]
  float*  bqkv  = (float*)(w2t + W1SZ);    // 1536 floats

  // prep
  cast_bf16<<<dim3((int)(SZ / 4 / 256)), dim3(256), 0, stream>>>(x, xb, (int)(SZ / 4));
  transpose_cast<<<dim3(16, 16), dim3(256), 0, stream>>>(wq, wqkvt, Dd, Dd);
  transpose_cast<<<dim3(16, 16), dim3(256), 0, stream>>>(wk, wkt, Dd, Dd);
  transpose_cast<<<dim3(16, 16), dim3(256), 0, stream>>>(wv, wvt, Dd, Dd);
  transpose_cast<<<dim3(16, 16), dim3(256), 0, stream>>>(wo, wot, Dd, Dd);
  transpose_cast<<<dim3(64, 16), dim3(256), 0, stream>>>(w1, w1t, Dd, Ff);
  transpose_cast<<<dim3(16, 64), dim3(256), 0, stream>>>(w2, w2t, Ff, Dd);
  concat3<<<dim3(6), dim3(256), 0, stream>>>(bq, bk, bvp, bqkv);

  const dim3 blk(256);
  // merged QKV: [8192,512] @ [512,1536] -> [8192,1536], 768 blocks = 3/CU
  gemm_mfma<true,  false><<<dim3(12, 64), blk, 0, stream>>>(xb, wqkvt, bqkv, qkvb, Mm, QT3, Dd);
  // attention (QTILE=128)
  flash_attn_mfma<<<dim3(32, 16), blk, 0, stream>>>(qkvb, ctxb);
  // out-proj (fp32 out for residual)
  gemm_mfma<false, false><<<dim3(4, 64), blk, 0, stream>>>(ctxb, wot, bo, attn_out, Mm, Dd, Dd);
  // LN1 (fp32 + bf16 copies)
  add_ln<true><<<dim3(8192), dim3(128), 0, stream>>>(x, attn_out, g1, be1, y, yb);
  // FFN
  gemm_mfma<true,  true ><<<dim3(16, 64), blk, 0, stream>>>(yb, w1t, b1, ffn1b, Mm, Ff, Dd);
  gemm_mfma<false, false><<<dim3(4, 64), blk, 0, stream>>>(ffn1b, w2t, b2, ffn2, Mm, Dd, Ff);
  // LN2
  add_ln<false><<<dim3(8192), dim3(128), 0, stream>>>(y, ffn2, g2, be2, out, (ushort*)nullptr);
}

// Round 10
// 427.435 us; speedup vs baseline: 4.4603x; 1.1801x over previous
//
#include <hip/hip_runtime.h>
#include <hip/hip_bf16.h>
#include <math.h>

#define Bb 2
#define Ss 4096
#define Dd 512
#define Hh 8
#define Ff 2048
#define Mm 8192   // Bb*Ss
#define QT3 1536  // 3*Dd, merged qkv row stride
#define KVB 128   // kv tile

typedef float  f32x4  __attribute__((ext_vector_type(4)));
typedef short  bf16x8 __attribute__((ext_vector_type(8)));

__device__ __forceinline__ ushort f2bf(float f) {
  union { float f; uint u; } c; c.f = f;
  uint u = c.u;
  uint r = (u + 0x7fffu + ((u >> 16) & 1u)) >> 16;  // RNE
  return (ushort)r;
}

// cheap round-half-up bf16 (for softmax P in [0, 2^8] — bias negligible)
__device__ __forceinline__ ushort f2bf_rhu(float f) {
  union { float f; uint u; } c; c.f = f;
  return (ushort)((c.u + 0x8000u) >> 16);
}

// async global->LDS, 16B per lane; LDS dest is wave-uniform base + lane*16
__device__ __forceinline__ void gload_lds16(const ushort* g, ushort* l) {
  __builtin_amdgcn_global_load_lds(
      (const __attribute__((address_space(1))) void*)g,
      (__attribute__((address_space(3))) void*)l, 16, 0, 0);
}

// ---------------------------------------------------------------------------
// bf16 MFMA GEMM (m97 structure): C[M,N] = A[M,K] @ Bt[N,K]^T + bias.
// 128x128 tile, BK=32, 256 thr = 4 waves (2x2 of 64x64), 4x4 16x16 frags/wave.
// ---------------------------------------------------------------------------
template<bool OUTBF, bool RELU>
__global__ __launch_bounds__(256) void gemm_mfma(const ushort* __restrict__ A,
                                                 const ushort* __restrict__ Bt,
                                                 const float* __restrict__ bias,
                                                 void* __restrict__ Cout,
                                                 int M, int N, int K) {
  __shared__ __align__(16) ushort As[128 * 32];
  __shared__ __align__(16) ushort Bs[128 * 32];
  const int t = threadIdx.x;
  const int w = t >> 6, lane = t & 63;
  const int lrow = lane & 15, lhi = lane >> 4;
  const int bm = blockIdx.y * 128, bn = blockIdx.x * 128;
  const int wm = (w >> 1) * 64, wn = (w & 1) * 64;
  const int sr = t >> 2, sc = (t & 3) * 8;   // staging: row, 8-elem col group

  f32x4 acc[4][4];
#pragma unroll
  for (int i = 0; i < 4; ++i)
#pragma unroll
    for (int j = 0; j < 4; ++j) acc[i][j] = (f32x4)(0.f);

  const ushort* Ap = A  + (size_t)(bm + sr) * K + sc;
  const ushort* Bp = Bt + (size_t)(bn + sr) * K + sc;
  const size_t rowK64 = (size_t)64 * K;
  ushort* AsW0 = As + w * 512;          // wave-uniform LDS bases
  ushort* AsW1 = As + 2048 + w * 512;
  ushort* BsW0 = Bs + w * 512;
  ushort* BsW1 = Bs + 2048 + w * 512;

  for (int k0 = 0; k0 < K; k0 += 32) {
    __syncthreads();
    gload_lds16(Ap + k0,          AsW0);
    gload_lds16(Ap + rowK64 + k0, AsW1);
    gload_lds16(Bp + k0,          BsW0);
    gload_lds16(Bp + rowK64 + k0, BsW1);
    __syncthreads();
    bf16x8 af[4], bfr[4];
#pragma unroll
    for (int i = 0; i < 4; ++i)
      af[i] = *(const bf16x8*)&As[(wm + i * 16 + lrow) * 32 + lhi * 8];
#pragma unroll
    for (int j = 0; j < 4; ++j)
      bfr[j] = *(const bf16x8*)&Bs[(wn + j * 16 + lrow) * 32 + lhi * 8];
#pragma unroll
    for (int i = 0; i < 4; ++i)
#pragma unroll
      for (int j = 0; j < 4; ++j)
        acc[i][j] = __builtin_amdgcn_mfma_f32_16x16x32_bf16(af[i], bfr[j], acc[i][j], 0, 0, 0);
  }

  float bvs[4];
#pragma unroll
  for (int j = 0; j < 4; ++j) bvs[j] = bias[bn + wn + j * 16 + lrow];

#pragma unroll
  for (int i = 0; i < 4; ++i)
#pragma unroll
    for (int r = 0; r < 4; ++r) {
      const int row = bm + wm + i * 16 + lhi * 4 + r;
#pragma unroll
      for (int j = 0; j < 4; ++j) {
        float val = acc[i][j][r] + bvs[j];
        if (RELU) val = fmaxf(val, 0.f);
        const size_t idx = (size_t)row * N + bn + wn + j * 16 + lrow;
        if (OUTBF) ((ushort*)Cout)[idx] = f2bf(val);
        else       ((float*)Cout)[idx]  = val;
      }
    }
}

// ---------------------------------------------------------------------------
// Causal flash attention v3: QTILE=64 (4 waves x 16 rows), KVB=128,
// exp2-domain online softmax with defer-max (THR=8, exact in fp32),
// per-lane deferred l-reduction, register-prefetched K/V staging,
// descending-qt launch. Input: merged qkv [Mm, 1536] bf16.
// LDS 52KB -> 3 blocks/CU (launch_bounds (256,3)).
// ---------------------------------------------------------------------------
__global__ __launch_bounds__(256, 3) void flash_attn_mfma(const ushort* __restrict__ qkv,
                                                          ushort* __restrict__ ctx) {
  __shared__ __align__(16) ushort Ks[128][72];   // [key][dim]
  __shared__ __align__(16) ushort Vt[64][136];   // [dim][key]
  __shared__ __align__(16) ushort Ps[4][16][136];

  const int t = threadIdx.x;
  const int w = t >> 6, lane = t & 63;
  const int lrow = lane & 15, lhi = lane >> 4;
  const int qt = (int)(gridDim.x - 1 - blockIdx.x);  // heavy blocks first
  const int bh = blockIdx.y;
  const int bb = bh >> 3, hh = bh & 7;
  const int q0 = qt * 64;
  const size_t baseq = (size_t)bb * Ss * QT3 + hh * 64;
  const ushort* qp = qkv + baseq;
  const ushort* kp = qkv + baseq + 512;
  const ushort* vp = qkv + baseq + 1024;

  const int krow = t >> 1, kd0 = (t & 1) * 32;   // K stager: 1 key, 32 dims
  const int vk0 = lane * 2, vd0 = w * 16;        // V stager: 2 keys, 16 dims

  // Q fragments: row q0 + w*16 + lrow
  bf16x8 qa[2];
  {
    const ushort* qsrc = qp + (size_t)(q0 + w * 16 + lrow) * QT3;
    qa[0] = *(const bf16x8*)(qsrc + lhi * 8);
    qa[1] = *(const bf16x8*)(qsrc + 32 + lhi * 8);
  }

  float m2[4], lsum[4];
  f32x4 oacc[4];
#pragma unroll
  for (int r = 0; r < 4; ++r) { m2[r] = -INFINITY; lsum[r] = 0.f; }
#pragma unroll
  for (int g = 0; g < 4; ++g) oacc[g] = (f32x4)(0.f);

  const int nt = (qt + 2) >> 1;          // ceil((qt+1)*64 / 128)
  const float C2 = 0.18033688f;          // 0.125 * log2(e)

  // register prefetch of tile 0
  bf16x8 kr[4], va[2], vb[2];
  {
    const ushort* ksrc = kp + (size_t)krow * QT3 + kd0;
#pragma unroll
    for (int j = 0; j < 4; ++j) kr[j] = *(const bf16x8*)(ksrc + j * 8);
    const ushort* vsrc = vp + (size_t)vk0 * QT3 + vd0;
    va[0] = *(const bf16x8*)(vsrc);
    va[1] = *(const bf16x8*)(vsrc + 8);
    vb[0] = *(const bf16x8*)(vsrc + QT3);
    vb[1] = *(const bf16x8*)(vsrc + QT3 + 8);
  }

  for (int kt = 0; kt < nt; ++kt) {
    const int j0 = kt * KVB;

    // ---- staged regs -> LDS ----
    __syncthreads();                     // all waves done with previous tile
#pragma unroll
    for (int j = 0; j < 4; ++j)
      *(bf16x8*)&Ks[krow][kd0 + j * 8] = kr[j];
#pragma unroll
    for (int i = 0; i < 8; ++i) {
      uint p0 = (uint)(ushort)va[0][i] | ((uint)(ushort)vb[0][i] << 16);
      uint p1 = (uint)(ushort)va[1][i] | ((uint)(ushort)vb[1][i] << 16);
      *(uint*)&Vt[vd0 + i][vk0]     = p0;
      *(uint*)&Vt[vd0 + 8 + i][vk0] = p1;
    }
    __syncthreads();                     // tile visible

    // ---- issue next tile's loads (hide latency under compute) ----
    if (kt + 1 < nt) {
      const int jn = j0 + KVB;
      const ushort* ksrc = kp + (size_t)(jn + krow) * QT3 + kd0;
#pragma unroll
      for (int j = 0; j < 4; ++j) kr[j] = *(const bf16x8*)(ksrc + j * 8);
      const ushort* vsrc = vp + (size_t)(jn + vk0) * QT3 + vd0;
      va[0] = *(const bf16x8*)(vsrc);
      va[1] = *(const bf16x8*)(vsrc + 8);
      vb[0] = *(const bf16x8*)(vsrc + QT3);
      vb[1] = *(const bf16x8*)(vsrc + QT3 + 8);
    }

    // ---- S = Q K^T (raw scores) ----
    f32x4 sacc[8];
#pragma unroll
    for (int g = 0; g < 8; ++g) sacc[g] = (f32x4)(0.f);
#pragma unroll
    for (int g = 0; g < 8; ++g)
#pragma unroll
      for (int kk = 0; kk < 2; ++kk) {
        bf16x8 kb = *(const bf16x8*)&Ks[g * 16 + lrow][kk * 32 + lhi * 8];
        sacc[g] = __builtin_amdgcn_mfma_f32_16x16x32_bf16(qa[kk], kb, sacc[g], 0, 0, 0);
      }

    // ---- causal mask (only tiles overlapping the diagonal) ----
    if (j0 + KVB - 1 > q0) {
#pragma unroll
      for (int g = 0; g < 8; ++g) {
        const int kcol = j0 + g * 16 + lrow;
#pragma unroll
        for (int r = 0; r < 4; ++r) {
          const int qrow = q0 + w * 16 + lhi * 4 + r;
          if (kcol > qrow) sacc[g][r] = -1e30f;
        }
      }
    }

    // ---- defer-max check (no cross-lane work in the common case) ----
    float pm[4];
#pragma unroll
    for (int r = 0; r < 4; ++r) {
      float m01 = fmaxf(sacc[0][r], sacc[1][r]);
      float m23 = fmaxf(sacc[2][r], sacc[3][r]);
      float m45 = fmaxf(sacc[4][r], sacc[5][r]);
      float m67 = fmaxf(sacc[6][r], sacc[7][r]);
      pm[r] = fmaxf(fmaxf(m01, m23), fmaxf(m45, m67));
    }
    bool ok = true;
#pragma unroll
    for (int r = 0; r < 4; ++r) ok = ok && (pm[r] * C2 <= m2[r] + 8.f);
    if (!__all(ok)) {
      // full path: exact max-reduce + rescale
      float mt2[4], alpha[4];
#pragma unroll
      for (int r = 0; r < 4; ++r) mt2[r] = pm[r] * C2;
#pragma unroll
      for (int off = 1; off <= 8; off <<= 1)
#pragma unroll
        for (int r = 0; r < 4; ++r)
          mt2[r] = fmaxf(mt2[r], __shfl_xor(mt2[r], off));
#pragma unroll
      for (int r = 0; r < 4; ++r) {
        const float mn = fmaxf(m2[r], mt2[r]);
        alpha[r] = exp2f(m2[r] - mn);    // exp2(-inf)=0 on first tile
        m2[r] = mn;
        lsum[r] *= alpha[r];
#pragma unroll
        for (int g = 0; g < 4; ++g) oacc[g][r] *= alpha[r];
      }
    }

    // ---- P = exp2(s*C2 - m2); per-lane l partials; write bf16 P ----
#pragma unroll
    for (int g = 0; g < 8; ++g)
#pragma unroll
      for (int r = 0; r < 4; ++r) {
        const float p = exp2f(fmaf(sacc[g][r], C2, -m2[r]));
        lsum[r] += p;
        Ps[w][lhi * 4 + r][g * 16 + lrow] = f2bf_rhu(p);
      }

    // ---- O += P V ----
    bf16x8 pa[4];
#pragma unroll
    for (int kk = 0; kk < 4; ++kk)
      pa[kk] = *(const bf16x8*)&Ps[w][lrow][kk * 32 + lhi * 8];
#pragma unroll
    for (int g = 0; g < 4; ++g)
#pragma unroll
      for (int kk = 0; kk < 4; ++kk) {
        bf16x8 vbb = *(const bf16x8*)&Vt[g * 16 + lrow][kk * 32 + lhi * 8];
        oacc[g] = __builtin_amdgcn_mfma_f32_16x16x32_bf16(pa[kk], vbb, oacc[g], 0, 0, 0);
      }
  }

  // ---- final l reduce (deferred across the whole loop) ----
#pragma unroll
  for (int off = 1; off <= 8; off <<= 1)
#pragma unroll
    for (int r = 0; r < 4; ++r)
      lsum[r] += __shfl_xor(lsum[r], off);

  // ---- normalize + write bf16 ctx [Mm, Dd] ----
  const size_t cbase = (size_t)bb * Ss * Dd + hh * 64;
#pragma unroll
  for (int r = 0; r < 4; ++r) {
    const float inv = 1.f / lsum[r];
    ushort* dst = ctx + cbase + (size_t)(q0 + w * 16 + lhi * 4 + r) * Dd;
#pragma unroll
    for (int g = 0; g < 4; ++g)
      dst[g * 16 + lrow] = f2bf(oacc[g][r] * inv);
  }
}

// ---------------------------------------------------------------------------
// out = LayerNorm(x + a) * g + b (fp32); optionally also bf16 copy.
// ---------------------------------------------------------------------------
template<bool WB>
__global__ __launch_bounds__(128) void add_ln(const float* __restrict__ x,
                                              const float* __restrict__ a,
                                              const float* __restrict__ g,
                                              const float* __restrict__ bta,
                                              float* __restrict__ out,
                                              ushort* __restrict__ outb) {
  __shared__ float red[4];
  const int row = blockIdx.x;
  const int tid = threadIdx.x;
  const size_t off = (size_t)row * Dd + tid * 4;
  const float4 xv = *(const float4*)(x + off);
  const float4 av = *(const float4*)(a + off);
  float4 sv;
  sv.x = xv.x + av.x; sv.y = xv.y + av.y; sv.z = xv.z + av.z; sv.w = xv.w + av.w;
  float sum = sv.x + sv.y + sv.z + sv.w;
  float sq  = sv.x * sv.x + sv.y * sv.y + sv.z * sv.z + sv.w * sv.w;
#pragma unroll
  for (int o = 32; o >= 1; o >>= 1) {
    sum += __shfl_down(sum, o);
    sq  += __shfl_down(sq, o);
  }
  if ((tid & 63) == 0) { red[(tid >> 6) * 2] = sum; red[(tid >> 6) * 2 + 1] = sq; }
  __syncthreads();
  const float tot = red[0] + red[2];
  const float tsq = red[1] + red[3];
  const float invD = 1.f / 512.f;
  const float mean = tot * invD;
  const float var  = tsq * invD - mean * mean;
  const float rs   = rsqrtf(var + 1e-3f);
  const float4 gv = *(const float4*)(g + tid * 4);
  const float4 bv = *(const float4*)(bta + tid * 4);
  float4 ov;
  ov.x = (sv.x - mean) * rs * gv.x + bv.x;
  ov.y = (sv.y - mean) * rs * gv.y + bv.y;
  ov.z = (sv.z - mean) * rs * gv.z + bv.z;
  ov.w = (sv.w - mean) * rs * gv.w + bv.w;
  *(float4*)(out + off) = ov;
  if (WB) {
    ushort4 ob = {f2bf(ov.x), f2bf(ov.y), f2bf(ov.z), f2bf(ov.w)};
    *(ushort4*)(outb + off) = ob;
  }
}

// ---------------------------------------------------------------------------
// prep kernels
// ---------------------------------------------------------------------------
__global__ __launch_bounds__(256) void cast_bf16(const float* __restrict__ in,
                                                 ushort* __restrict__ out, int n4) {
  const int i = blockIdx.x * 256 + threadIdx.x;
  if (i < n4) {
    const float4 vin = ((const float4*)in)[i];
    ushort4 o = {f2bf(vin.x), f2bf(vin.y), f2bf(vin.z), f2bf(vin.w)};
    ((ushort4*)out)[i] = o;
  }
}

__global__ __launch_bounds__(256) void transpose_cast(const float* __restrict__ W,
                                                      ushort* __restrict__ Wt,
                                                      int K, int N) {
  __shared__ float tile[32][33];
  const int bk = blockIdx.y * 32, bn = blockIdx.x * 32;
  const int tx = threadIdx.x & 31, ty = threadIdx.x >> 5;
#pragma unroll
  for (int i = 0; i < 32; i += 8)
    tile[ty + i][tx] = W[(size_t)(bk + ty + i) * N + bn + tx];
  __syncthreads();
#pragma unroll
  for (int i = 0; i < 32; i += 8)
    Wt[(size_t)(bn + ty + i) * K + bk + tx] = f2bf(tile[tx][ty + i]);
}

__global__ __launch_bounds__(256) void concat3(const float* __restrict__ a,
                                               const float* __restrict__ b,
                                               const float* __restrict__ c,
                                               float* __restrict__ o) {
  const int i = blockIdx.x * 256 + threadIdx.x;  // 1536 total
  if (i < 512) o[i] = a[i];
  else if (i < 1024) o[i] = b[i - 512];
  else if (i < 1536) o[i] = c[i - 1024];
}

// ---------------------------------------------------------------------------
extern "C" void kernel_launch(void* const* d_in, const int* in_sizes, int n_in,
                              void* d_out, int out_size, void* d_ws, size_t ws_size,
                              hipStream_t stream) {
  (void)in_sizes; (void)n_in; (void)out_size; (void)ws_size;
  const float* x   = (const float*)d_in[0];
  // d_in[1] = mask: causal, applied analytically
  const float* wq  = (const float*)d_in[2];
  const float* bq  = (const float*)d_in[3];
  const float* wk  = (const float*)d_in[4];
  const float* bk  = (const float*)d_in[5];
  const float* wv  = (const float*)d_in[6];
  const float* bvp = (const float*)d_in[7];
  const float* wo  = (const float*)d_in[8];
  const float* bo  = (const float*)d_in[9];
  const float* g1  = (const float*)d_in[10];
  const float* be1 = (const float*)d_in[11];
  const float* w1  = (const float*)d_in[12];
  const float* b1  = (const float*)d_in[13];
  const float* w2  = (const float*)d_in[14];
  const float* b2  = (const float*)d_in[15];
  const float* g2  = (const float*)d_in[16];
  const float* be2 = (const float*)d_in[17];
  float* out = (float*)d_out;

  const size_t SZ  = (size_t)Mm * Dd;      // 4,194,304
  const size_t WSZ = (size_t)Dd * Dd;      // 262,144
  const size_t W1SZ = (size_t)Dd * Ff;     // 1,048,576

  float* fp = (float*)d_ws;
  float* attn_out = fp;                    // fp32 SZ
  float* y        = fp + SZ;               // fp32 SZ
  float* ffn2     = fp + 2 * SZ;           // fp32 SZ
  ushort* ub   = (ushort*)(fp + 3 * SZ);
  ushort* xb    = ub;                      // SZ
  ushort* qkvb  = ub + SZ;                 // 3*SZ  (8192 x 1536)
  ushort* ctxb  = ub + 4 * SZ;             // SZ
  ushort* yb    = ub + 5 * SZ;             // SZ
  ushort* ffn1b = ub + 6 * SZ;             // 4*SZ  (8192 x 2048)
  ushort* wqkvt = ub + 10 * SZ;            // 3*WSZ: [1536,512] = wq^T|wk^T|wv^T
  ushort* wkt   = wqkvt + WSZ;
  ushort* wvt   = wkt + WSZ;
  ushort* wot   = wqkvt + 3 * WSZ;         // WSZ
  ushort* w1t   = wot + WSZ;               // W1SZ [2048,512]
  ushort* w2t   = w1t + W1SZ;              // W1SZ [512,2048]
  float*  bqkv  = (float*)(w2t + W1SZ);    // 1536 floats

  // prep
  cast_bf16<<<dim3((int)(SZ / 4 / 256)), dim3(256), 0, stream>>>(x, xb, (int)(SZ / 4));
  transpose_cast<<<dim3(16, 16), dim3(256), 0, stream>>>(wq, wqkvt, Dd, Dd);
  transpose_cast<<<dim3(16, 16), dim3(256), 0, stream>>>(wk, wkt, Dd, Dd);
  transpose_cast<<<dim3(16, 16), dim3(256), 0, stream>>>(wv, wvt, Dd, Dd);
  transpose_cast<<<dim3(16, 16), dim3(256), 0, stream>>>(wo, wot, Dd, Dd);
  transpose_cast<<<dim3(64, 16), dim3(256), 0, stream>>>(w1, w1t, Dd, Ff);
  transpose_cast<<<dim3(16, 64), dim3(256), 0, stream>>>(w2, w2t, Ff, Dd);
  concat3<<<dim3(6), dim3(256), 0, stream>>>(bq, bk, bvp, bqkv);

  const dim3 blk(256);
  // merged QKV: [8192,512] @ [512,1536] -> [8192,1536]
  gemm_mfma<true,  false><<<dim3(12, 64), blk, 0, stream>>>(xb, wqkvt, bqkv, qkvb, Mm, QT3, Dd);
  // attention (QTILE=64, KVB=128)
  flash_attn_mfma<<<dim3(64, 16), blk, 0, stream>>>(qkvb, ctxb);
  // out-proj (fp32 out for residual)
  gemm_mfma<false, false><<<dim3(4, 64), blk, 0, stream>>>(ctxb, wot, bo, attn_out, Mm, Dd, Dd);
  // LN1 (fp32 + bf16 copies)
  add_ln<true><<<dim3(8192), dim3(128), 0, stream>>>(x, attn_out, g1, be1, y, yb);
  // FFN
  gemm_mfma<true,  true ><<<dim3(16, 64), blk, 0, stream>>>(yb, w1t, b1, ffn1b, Mm, Ff, Dd);
  gemm_mfma<false, false><<<dim3(4, 64), blk, 0, stream>>>(ffn1b, w2t, b2, ffn2, Mm, Dd, Ff);
  // LN2
  add_ln<false><<<dim3(8192), dim3(128), 0, stream>>>(y, ffn2, g2, be2, out, (ushort*)nullptr);
}